// Round 2
// baseline (644.515 us; speedup 1.0000x reference)
//
#include <hip/hip_runtime.h>
#include <stdint.h>

#define NN 100000
#define EE 1600000
#define IN_C 128
#define HID_C 256
#define OUT_C 64

#define NB 391            // CSR buckets: 256 node-ids each (391*256 = 100096 >= NN)
#define CAP 5120          // LDS sort capacity per bucket (expected 4096, +16 sigma)
#define K3_NPT 25         // edges per thread in bucket kernels
#define K3_BLOCKS 250     // 250 * 256 * 25 = 1.6M = EE exactly

typedef unsigned short bf16_t;
typedef unsigned int u32;
typedef __attribute__((ext_vector_type(8))) short bf16x8;
typedef __attribute__((ext_vector_type(4))) float f32x4;

__device__ __forceinline__ float b2f(unsigned short u){
  unsigned int x = ((unsigned int)u) << 16;
  return __uint_as_float(x);
}
__device__ __forceinline__ unsigned short f2b(float f){
  unsigned int x = __float_as_uint(f);
  unsigned int r = x + 0x7FFFu + ((x >> 16) & 1u);   // RNE
  return (unsigned short)(r >> 16);
}

// async global->LDS, 16B per lane. LDS dest is wave-uniform base + lane*16.
#define GL16(gp, lp) __builtin_amdgcn_global_load_lds( \
    (const __attribute__((address_space(1))) void*)(gp), \
    (__attribute__((address_space(3))) void*)(lp), 16, 0, 0)

// ---------------- edge dtype detector ----------------
__global__ void detect_edge_k(const int* __restrict__ ei, int* __restrict__ eflag){
  __shared__ int sm[256];
  int t = threadIdx.x;
  int o = 0;
  for (int i = t; i < 1024; i += 256) o |= ei[2*i + 1];
  sm[t] = o; __syncthreads();
  for (int s = 128; s > 0; s >>= 1){
    if (t < s) sm[t] |= sm[t + s];
    __syncthreads();
  }
  if (t == 0) *eflag = (sm[0] == 0) ? 1 : 0;   // 1 = int64 layout
}

// ---------------- CSR build: bucketed two-phase sort ----------------
// K1: per-bucket edge counts (LDS histogram, few global atomics)
__global__ __launch_bounds__(256) void bcount_k(const int* __restrict__ ei,
    const int* __restrict__ eflag, int* __restrict__ bcnt){
  __shared__ int h[NB];
  int t = threadIdx.x;
  for (int i = t; i < NB; i += 256) h[i] = 0;
  __syncthreads();
  int i64 = *eflag;
  int base = blockIdx.x * (256 * K3_NPT);
  #pragma unroll
  for (int q = 0; q < K3_NPT; ++q){
    int e = base + q * 256 + t;
    int d = i64 ? ei[2*(EE + e)] : ei[EE + e];
    atomicAdd(&h[d >> 8], 1);
  }
  __syncthreads();
  for (int i = t; i < NB; i += 256) if (h[i]) atomicAdd(&bcnt[i], h[i]);
}

// K2: exclusive scan of bucket counts -> bbase[0..NB]
__global__ void bscan_k(const int* __restrict__ bcnt, int* __restrict__ bbase){
  __shared__ int sm[512];
  int t = threadIdx.x;
  sm[t] = (t < NB) ? bcnt[t] : 0;
  __syncthreads();
  for (int off = 1; off < 512; off <<= 1){
    int a = (t >= off) ? sm[t - off] : 0;
    __syncthreads();
    sm[t] += a;
    __syncthreads();
  }
  if (t <= NB) bbase[t] = (t == 0) ? 0 : sm[t - 1];
}

// K3: scatter (src,dst) into bucket-grouped pairs with per-(block,bucket)
// reservations -> writes are sequential runs (L2 line-merge friendly)
__global__ __launch_bounds__(256) void bscatter_k(const int* __restrict__ ei,
    const int* __restrict__ eflag, const int* __restrict__ bbase,
    int* __restrict__ bfill, uint2* __restrict__ pairs){
  __shared__ int cnt[NB];
  __shared__ int cnt2[NB];
  __shared__ int lbase[NB];
  int t = threadIdx.x;
  for (int i = t; i < NB; i += 256){ cnt[i] = 0; cnt2[i] = 0; }
  __syncthreads();
  int i64 = *eflag;
  int ebase = blockIdx.x * (256 * K3_NPT);
  int src[K3_NPT], dst[K3_NPT];
  #pragma unroll
  for (int q = 0; q < K3_NPT; ++q){
    int e = ebase + q * 256 + t;
    src[q] = i64 ? ei[2*e] : ei[e];
    dst[q] = i64 ? ei[2*(EE + e)] : ei[EE + e];
    atomicAdd(&cnt[dst[q] >> 8], 1);
  }
  __syncthreads();
  for (int i = t; i < NB; i += 256)
    lbase[i] = cnt[i] ? atomicAdd(&bfill[i], cnt[i]) : 0;
  __syncthreads();
  #pragma unroll
  for (int q = 0; q < K3_NPT; ++q){
    int b = dst[q] >> 8;
    int r = atomicAdd(&cnt2[b], 1);
    pairs[bbase[b] + lbase[b] + r] = make_uint2((u32)src[q], (u32)dst[q]);
  }
}

// K4: per-bucket counting sort in LDS -> coalesced csr + rowptr writes
__global__ __launch_bounds__(256) void bsort_k(const uint2* __restrict__ pairs,
    const int* __restrict__ bbase, int* __restrict__ rowptr, int* __restrict__ csr){
  __shared__ int hist[256];
  __shared__ int pref[257];
  __shared__ int cnt[256];
  __shared__ int lsrc[CAP];
  int b = blockIdx.x;
  int t = threadIdx.x;
  int e0 = bbase[b], e1 = bbase[b + 1];
  int s = e1 - e0;
  hist[t] = 0; cnt[t] = 0;
  __syncthreads();
  for (int i = t; i < s; i += 256)
    atomicAdd(&hist[pairs[e0 + i].y & 255], 1);
  __syncthreads();
  // inclusive scan of hist
  for (int off = 1; off < 256; off <<= 1){
    int a = (t >= off) ? hist[t - off] : 0;
    __syncthreads();
    hist[t] += a;
    __syncthreads();
  }
  if (t == 0) pref[0] = 0;
  pref[t + 1] = hist[t];
  __syncthreads();
  // rowptr: global node id = b*256 + t (guard <= NN; bucket b+1 rewrites its own base)
  int gid = b * 256 + t;
  if (gid <= NN) rowptr[gid] = e0 + pref[t];
  // counting-sort scatter into LDS (spill path for oversized buckets)
  for (int i = t; i < s; i += 256){
    uint2 p = pairs[e0 + i];
    int bin = p.y & 255;
    int r = atomicAdd(&cnt[bin], 1);
    int pos = pref[bin] + r;
    if (pos < CAP) lsrc[pos] = (int)p.x;
    else           csr[e0 + pos] = (int)p.x;
  }
  __syncthreads();
  int lim = s < CAP ? s : CAP;
  for (int i = t; i < lim; i += 256) csr[e0 + i] = lsrc[i];
}

// ---------------- dtype conversion ----------------

__global__ void f2b_vec_k(const float* __restrict__ in, bf16_t* __restrict__ out, int n){
  int g = blockIdx.x * 256 + threadIdx.x;
  int i = g * 4;
  if (i < n){
    float4 v = *(const float4*)(in + i);
    uint2 u;
    u.x = (u32)f2b(v.x) | ((u32)f2b(v.y) << 16);
    u.y = (u32)f2b(v.z) | ((u32)f2b(v.w) << 16);
    *(uint2*)(out + i) = u;
  }
}

struct WtArgs {
  const float* W[6];
  bf16_t* Wt[6];
  int K[6], N[6];
  int off[7];
};

__global__ void wt_all_k(WtArgs a){
  int g = blockIdx.x * 256 + threadIdx.x;
  if (g >= a.off[6]) return;
  #pragma unroll
  for (int s = 0; s < 6; ++s){
    if (g >= a.off[s] && g < a.off[s + 1]){
      int local = g - a.off[s];
      int K = a.K[s], N = a.N[s];
      int n = local / K, k = local - n * K;
      a.Wt[s][local] = f2b(a.W[s][(size_t)k * N + n]);
    }
  }
}

// ---------------- per-row quantization: one wave per row ----------------

template<int C, bool SIGNED, typename TIN>
__global__ __launch_bounds__(256) void quant_k(const TIN* __restrict__ in,
    uint8_t* __restrict__ outq, float* __restrict__ scales){
  constexpr int V = C / 64;
  int row  = (blockIdx.x * 256 + threadIdx.x) >> 6;
  int lane = threadIdx.x & 63;
  if (row >= NN) return;
  float v[V];
  if constexpr (sizeof(TIN) == 4){
    float2 u = *(const float2*)((const float*)in + (size_t)row * C + lane * 2);
    v[0] = u.x; v[1] = u.y;
  } else {
    const bf16_t* bp = (const bf16_t*)in + (size_t)row * C + lane * V;
    if constexpr (V == 4){
      uint2 u = *(const uint2*)bp;
      v[0] = b2f((unsigned short)(u.x & 0xffffu)); v[1] = b2f((unsigned short)(u.x >> 16));
      v[2] = b2f((unsigned short)(u.y & 0xffffu)); v[3] = b2f((unsigned short)(u.y >> 16));
    } else if constexpr (V == 2){
      u32 u = *(const u32*)bp;
      v[0] = b2f((unsigned short)(u & 0xffffu)); v[1] = b2f((unsigned short)(u >> 16));
    } else {
      v[0] = b2f(*bp);
    }
  }
  float m = 0.f;
  #pragma unroll
  for (int i = 0; i < V; ++i) m = fmaxf(m, SIGNED ? fabsf(v[i]) : v[i]);
  #pragma unroll
  for (int msk = 1; msk < 64; msk <<= 1) m = fmaxf(m, __shfl_xor(m, msk, 64));
  const float qmax = SIGNED ? 127.f : 255.f;
  float inv = m > 0.f ? qmax / m : 0.f;
  uint8_t qb[V];
  #pragma unroll
  for (int i = 0; i < V; ++i){
    float qf = rintf(v[i] * inv);
    if (SIGNED){
      qf = fminf(fmaxf(qf, -127.f), 127.f);
      qb[i] = (uint8_t)(int8_t)(int)qf;
    } else {
      qf = fminf(fmaxf(qf, 0.f), 255.f);
      qb[i] = (uint8_t)(int)qf;
    }
  }
  uint8_t* op = outq + (size_t)row * C + lane * V;
  if constexpr (V == 4){
    u32 p = (u32)qb[0] | ((u32)qb[1] << 8) | ((u32)qb[2] << 16) | ((u32)qb[3] << 24);
    *(u32*)op = p;
  } else if constexpr (V == 2){
    *(unsigned short*)op = (unsigned short)((u32)qb[0] | ((u32)qb[1] << 8));
  } else {
    *op = qb[0];
  }
  if (lane == 0) scales[row] = m / qmax;
}

// ---------------- mean aggregation over quantized rows ----------------
// Latency-optimized: 16-wide batches, no scalar tail. Out-of-range edges
// clamp to the last edge (same-address loads, broadcast-cheap) with scale 0.

__device__ __forceinline__ float qdec(u32 w, int b, bool sgn){
  u32 byte = (w >> (8 * b)) & 0xffu;
  return sgn ? (float)(int8_t)byte : (float)byte;
}

template<int C, bool SIGNED>
__global__ __launch_bounds__(256) void agg_q8_k(const uint8_t* __restrict__ tq,
    const float* __restrict__ tsc,
    const int* __restrict__ rowptr, const int* __restrict__ csr,
    bf16_t* __restrict__ outm){
  constexpr int V = C / 64;
  constexpr int B = 16;
  int wid  = (blockIdx.x * 256 + threadIdx.x) >> 6;
  int lane = threadIdx.x & 63;
  if (wid >= NN) return;
  int beg = __builtin_amdgcn_readfirstlane(rowptr[wid]);
  int end = __builtin_amdgcn_readfirstlane(rowptr[wid + 1]);
  float acc[V];
  #pragma unroll
  for (int i = 0; i < V; ++i) acc[i] = 0.f;

  const uint8_t* hb = tq + lane * V;
  int last = end - 1;
  for (int e = beg; e < end; e += B){
    int s[B]; float sc[B]; u32 w[B];
    #pragma unroll
    for (int q = 0; q < B; ++q){
      int idx = e + q;
      idx = idx < last ? idx : last;
      s[q] = csr[idx];
    }
    #pragma unroll
    for (int q = 0; q < B; ++q){
      if constexpr (V == 4) w[q] = *(const u32*)(hb + (size_t)s[q] * C);
      else                  w[q] = *(const unsigned short*)(hb + (size_t)s[q] * C);
      sc[q] = (e + q < end) ? tsc[s[q]] : 0.f;
    }
    #pragma unroll
    for (int q = 0; q < B; ++q)
      #pragma unroll
      for (int i = 0; i < V; ++i)
        acc[i] += sc[q] * qdec(w[q], i, SIGNED);
  }

  int d = end - beg;
  float di = d > 0 ? 1.0f / (float)d : 0.f;
  bf16_t* po = outm + (size_t)wid * C + lane * V;
  if constexpr (V == 2){
    u32 u = (u32)f2b(acc[0] * di) | ((u32)f2b(acc[1] * di) << 16);
    *(u32*)po = u;
  } else {
    uint2 u;
    u.x = (u32)f2b(acc[0] * di) | ((u32)f2b(acc[1] * di) << 16);
    u.y = (u32)f2b(acc[2] * di) | ((u32)f2b(acc[3] * di) << 16);
    *(uint2*)po = u;
  }
}

// ---------------- final aggregation (layer 3, C=64, int8 P) ----------------

__global__ __launch_bounds__(256) void agg_final_q8_k(
    const uint8_t* __restrict__ Pq, const float* __restrict__ scp,
    const float* __restrict__ Q,
    const int* __restrict__ rowptr, const int* __restrict__ csr,
    float* __restrict__ out){
  constexpr int B = 16;
  int wid  = (blockIdx.x * 256 + threadIdx.x) >> 6;
  int lane = threadIdx.x & 63;
  if (wid >= NN) return;
  int beg = __builtin_amdgcn_readfirstlane(rowptr[wid]);
  int end = __builtin_amdgcn_readfirstlane(rowptr[wid + 1]);
  const uint8_t* Pb = Pq + lane;
  float acc = 0.f;
  int last = end - 1;
  for (int e = beg; e < end; e += B){
    int s[B]; uint8_t b[B]; float sc[B];
    #pragma unroll
    for (int q = 0; q < B; ++q){
      int idx = e + q;
      idx = idx < last ? idx : last;
      s[q] = csr[idx];
    }
    #pragma unroll
    for (int q = 0; q < B; ++q){
      b[q] = Pb[(size_t)s[q] * 64];
      sc[q] = (e + q < end) ? scp[s[q]] : 0.f;
    }
    #pragma unroll
    for (int q = 0; q < B; ++q) acc += sc[q] * (float)(int8_t)b[q];
  }
  int d = end - beg;
  float di = d > 0 ? 1.0f / (float)d : 0.f;
  out[(size_t)wid * 64 + lane] = acc * di + Q[(size_t)wid * 64 + lane];
}

// ---------------- MFMA dual-GEMM + bias + BN + ReLU (layers 1,2) ----------------
// 2-phase pipeline: global_load_lds(16B) staging into XOR-swizzled linear LDS,
// double-buffered, counted s_waitcnt vmcnt(8) (never drained mid-loop),
// raw s_barrier (no compiler vmcnt(0) drain).
// LDS layout: chunk c (16B) at offset c*16, c = row*8 + slot, slot = k8 ^ (row&7).
// Staging inverse-swizzles the *global* source so reads swizzle symmetrically.

template<int K_>
__global__ __launch_bounds__(256) void mfma_gemm_k(
    const bf16_t* __restrict__ A0, const bf16_t* __restrict__ A1,
    const bf16_t* __restrict__ W0t, const bf16_t* __restrict__ W1t,
    const float* __restrict__ bias,
    const float* __restrict__ gamma, const float* __restrict__ beta,
    const float* __restrict__ rmean, const float* __restrict__ rvar,
    bf16_t* __restrict__ out, int M, int Nout)
{
  constexpr int BM = 128;
  constexpr int BN = 128;
  constexpr int BK = 64;
  constexpr int KT = K_ / BK;     // k-tiles per pass
  constexpr int T  = 2 * KT;      // total tiles across both passes
  __shared__ bf16_t As[2][BM * BK];
  __shared__ bf16_t Bs[2][BN * BK];

  int t    = threadIdx.x;
  int lane = t & 63;
  int wid  = t >> 6;
  int wr   = wid >> 1, wc = wid & 1;
  int l15  = lane & 15;
  int quad = lane >> 4;

  int m0 = blockIdx.x * BM;
  int n0 = blockIdx.y * BN;

  f32x4 acc[4][4];
  #pragma unroll
  for (int i = 0; i < 4; ++i)
    #pragma unroll
    for (int j = 0; j < 4; ++j)
      acc[i][j] = (f32x4){0.f, 0.f, 0.f, 0.f};

  auto stage = [&](int tile, int buf){
    const bf16_t* Ap = (tile < KT) ? A0 : A1;
    const bf16_t* Wp = (tile < KT) ? W0t : W1t;
    int k0 = ((tile < KT) ? tile : tile - KT) * BK;
    #pragma unroll
    for (int i = 0; i < 4; ++i){           // A: 1024 chunks, 4 gload/wave
      int c   = i * 256 + t;
      int row = c >> 3;
      int k8  = (c & 7) ^ (row & 7);
      int gm  = m0 + row; gm = gm < NN ? gm : NN - 1;
      GL16(Ap + (size_t)gm * K_ + k0 + k8 * 8, &As[buf][(i * 256 + (t & 192)) * 8]);
    }
    #pragma unroll
    for (int i = 0; i < 4; ++i){           // B: 1024 chunks, 4 gload/wave
      int c   = i * 256 + t;
      int row = c >> 3;
      int k8  = (c & 7) ^ (row & 7);
      GL16(Wp + (size_t)(n0 + row) * K_ + k0 + k8 * 8, &Bs[buf][(i * 256 + (t & 192)) * 8]);
    }
  };

  stage(0, 0);
  #pragma unroll
  for (int tile = 0; tile < T; ++tile){
    int buf = tile & 1;
    if (tile + 1 < T){
      stage(tile + 1, buf ^ 1);                        // issue next, no wait
      asm volatile("s_waitcnt vmcnt(8)" ::: "memory"); // current tile's 8 landed
    } else {
      asm volatile("s_waitcnt vmcnt(0)" ::: "memory");
    }
    __builtin_amdgcn_s_barrier();                      // all waves' chunks visible
    #pragma unroll
    for (int kk = 0; kk < 2; ++kk){
      bf16x8 af[4], bfr[4];
      #pragma unroll
      for (int i = 0; i < 4; ++i){
        int row = wr * 64 + i * 16 + l15;
        af[i] = *(const bf16x8*)(&As[buf][(size_t)((row << 3) + ((quad + kk * 4) ^ (row & 7))) * 8]);
      }
      #pragma unroll
      for (int j = 0; j < 4; ++j){
        int row = wc * 64 + j * 16 + l15;
        bfr[j] = *(const bf16x8*)(&Bs[buf][(size_t)((row << 3) + ((quad + kk * 4) ^ (row & 7))) * 8]);
      }
      #pragma unroll
      for (int i = 0; i < 4; ++i)
        #pragma unroll
        for (int j = 0; j < 4; ++j)
          acc[i][j] = __builtin_amdgcn_mfma_f32_16x16x32_bf16(af[i], bfr[j], acc[i][j], 0, 0, 0);
    }
    __builtin_amdgcn_s_barrier();                      // protect buf before overwrite
  }

  #pragma unroll
  for (int j = 0; j < 4; ++j){
    int col = n0 + wc * 64 + j * 16 + l15;
    float sc = gamma[col] * rsqrtf(rvar[col] + 1e-5f);
    float shift = (bias[col] - rmean[col]) * sc + beta[col];
    #pragma unroll
    for (int i = 0; i < 4; ++i){
      int rbase = m0 + wr * 64 + i * 16 + quad * 4;
      #pragma unroll
      for (int r = 0; r < 4; ++r){
        int row = rbase + r;
        if (row < M){
          float v = fmaxf(acc[i][j][r] * sc + shift, 0.f);
          out[(size_t)row * Nout + col] = f2b(v);
        }
      }
    }
  }
}

// ---------------- layer-3 single-A GEMM: P = A@Wcl (bf16), Q = A@Wcr + bcl (f32) ----------------
// Same 2-phase global_load_lds pipeline, single pass, K=256.

__global__ __launch_bounds__(256) void gemm3_k(
    const bf16_t* __restrict__ A, const bf16_t* __restrict__ Wt,
    const float* __restrict__ bcl,
    bf16_t* __restrict__ P, float* __restrict__ Q, int M)
{
  constexpr int K_ = 256, BM = 128, BN = 128, BK = 64;
  constexpr int T = K_ / BK;      // 4 tiles
  __shared__ bf16_t As[2][BM * BK];
  __shared__ bf16_t Bs[2][BN * BK];

  int t    = threadIdx.x;
  int lane = t & 63;
  int wid  = t >> 6;
  int wr   = wid >> 1, wc = wid & 1;
  int l15  = lane & 15;
  int quad = lane >> 4;
  int m0 = blockIdx.x * BM;

  f32x4 acc[4][4];
  #pragma unroll
  for (int i = 0; i < 4; ++i)
    #pragma unroll
    for (int j = 0; j < 4; ++j)
      acc[i][j] = (f32x4){0.f, 0.f, 0.f, 0.f};

  auto stage = [&](int tile, int buf){
    int k0 = tile * BK;
    #pragma unroll
    for (int i = 0; i < 4; ++i){
      int c   = i * 256 + t;
      int row = c >> 3;
      int k8  = (c & 7) ^ (row & 7);
      int gm  = m0 + row; gm = gm < NN ? gm : NN - 1;
      GL16(A + (size_t)gm * K_ + k0 + k8 * 8, &As[buf][(i * 256 + (t & 192)) * 8]);
    }
    #pragma unroll
    for (int i = 0; i < 4; ++i){
      int c   = i * 256 + t;
      int row = c >> 3;
      int k8  = (c & 7) ^ (row & 7);
      GL16(Wt + (size_t)row * K_ + k0 + k8 * 8, &Bs[buf][(i * 256 + (t & 192)) * 8]);
    }
  };

  stage(0, 0);
  #pragma unroll
  for (int tile = 0; tile < T; ++tile){
    int buf = tile & 1;
    if (tile + 1 < T){
      stage(tile + 1, buf ^ 1);
      asm volatile("s_waitcnt vmcnt(8)" ::: "memory");
    } else {
      asm volatile("s_waitcnt vmcnt(0)" ::: "memory");
    }
    __builtin_amdgcn_s_barrier();
    #pragma unroll
    for (int kk = 0; kk < 2; ++kk){
      bf16x8 af[4], bfr[4];
      #pragma unroll
      for (int i = 0; i < 4; ++i){
        int row = wr * 64 + i * 16 + l15;
        af[i] = *(const bf16x8*)(&As[buf][(size_t)((row << 3) + ((quad + kk * 4) ^ (row & 7))) * 8]);
      }
      #pragma unroll
      for (int j = 0; j < 4; ++j){
        int row = wc * 64 + j * 16 + l15;
        bfr[j] = *(const bf16x8*)(&Bs[buf][(size_t)((row << 3) + ((quad + kk * 4) ^ (row & 7))) * 8]);
      }
      #pragma unroll
      for (int i = 0; i < 4; ++i)
        #pragma unroll
        for (int j = 0; j < 4; ++j)
          acc[i][j] = __builtin_amdgcn_mfma_f32_16x16x32_bf16(af[i], bfr[j], acc[i][j], 0, 0, 0);
    }
    __builtin_amdgcn_s_barrier();
  }

  #pragma unroll
  for (int j = 0; j < 4; ++j){
    int col = wc * 64 + j * 16 + l15;      // 0..127
    #pragma unroll
    for (int i = 0; i < 4; ++i){
      int rbase = m0 + wr * 64 + i * 16 + quad * 4;
      #pragma unroll
      for (int r = 0; r < 4; ++r){
        int row = rbase + r;
        if (row < M){
          float v = acc[i][j][r];
          if (col < 64) P[(size_t)row * 64 + col] = f2b(v);
          else          Q[(size_t)row * 64 + (col - 64)] = v + bcl[col - 64];
        }
      }
    }
  }
}

// ---------------- launch ----------------

extern "C" void kernel_launch(void* const* d_in, const int* in_sizes, int n_in,
                              void* d_out, int out_size, void* d_ws, size_t ws_size,
                              hipStream_t stream)
{
  const float* x   = (const float*)d_in[0];
  const int*   ei  = (const int*)d_in[1];
  const float* W1l = (const float*)d_in[2];
  const float* b1l = (const float*)d_in[3];
  const float* W1r = (const float*)d_in[4];
  const float* g1  = (const float*)d_in[5];
  const float* be1 = (const float*)d_in[6];
  const float* rm1 = (const float*)d_in[7];
  const float* rv1 = (const float*)d_in[8];
  const float* W2l = (const float*)d_in[9];
  const float* b2l = (const float*)d_in[10];
  const float* W2r = (const float*)d_in[11];
  const float* g2  = (const float*)d_in[12];
  const float* be2 = (const float*)d_in[13];
  const float* rm2 = (const float*)d_in[14];
  const float* rv2 = (const float*)d_in[15];
  const float* Wcl = (const float*)d_in[16];
  const float* bcl = (const float*)d_in[17];
  const float* Wcr = (const float*)d_in[18];
  (void)in_sizes; (void)n_in; (void)out_size; (void)ws_size;

  char* ws = (char*)d_ws;
  size_t off = 0;
  auto alloc = [&](size_t bytes)->char* {
    char* p = ws + off;
    off += (bytes + 15) & ~(size_t)15;
    return p;
  };
  int*    bcnt   = (int*)   alloc(800 * 4);             // [NB] counts + [NB] fill (contig)
  int*    bfill  = bcnt + 400;
  int*    bbase  = (int*)   alloc((size_t)(NB + 1) * 4);
  int*    rowptr = (int*)   alloc((size_t)(NN + 1) * 4);
  int*    eflag  = (int*)   alloc(16);
  int*    csr    = (int*)   alloc((size_t)EE * 4);
  bf16_t* xb     = (bf16_t*)alloc((size_t)NN * IN_C * 2);
  bf16_t* aggb   = (bf16_t*)alloc((size_t)NN * HID_C * 2);
  bf16_t* h1     = (bf16_t*)alloc((size_t)NN * HID_C * 2);
  bf16_t* h2     = (bf16_t*)alloc((size_t)NN * HID_C * 2);
  bf16_t* W1lt   = (bf16_t*)alloc((size_t)IN_C  * HID_C * 2);
  bf16_t* W1rt   = (bf16_t*)alloc((size_t)IN_C  * HID_C * 2);
  bf16_t* W2lt   = (bf16_t*)alloc((size_t)HID_C * HID_C * 2);
  bf16_t* W2rt   = (bf16_t*)alloc((size_t)HID_C * HID_C * 2);
  bf16_t* Wc3t   = (bf16_t*)alloc((size_t)128 * HID_C * 2);  // [128][256] concat
  float*  sc1    = (float*) alloc((size_t)NN * 4);           // h1 row scales
  float*  scp    = (float*) alloc((size_t)NN * 4);           // P row scales

  // aliases into dead-by-then regions:
  uint2*   pairs = (uint2*)aggb;                     // [E] (src,dst), CSR build only
  uint8_t* xq  = (uint8_t*)h2;                       // [N,128] s8, dead before GEMM2 writes h2
  float*   scx = (float*)((char*)h2 + (size_t)NN * IN_C);
  uint8_t* h1q = (uint8_t*)xb;                       // [N,256] u8, xb dead after GEMM1
  bf16_t*  P   = xb;                                 // [N,64] bf16, h1q dead after layer-2 agg
  uint8_t* Pq  = (uint8_t*)aggb;                     // [N,64] s8, aggb dead after GEMM2
  float*   Q   = (float*)h1;                         // [N,64] f32, h1 dead after GEMM2

  hipMemsetAsync(bcnt, 0, 800 * 4, stream);

  // conversions
  f2b_vec_k<<<(NN * IN_C / 4 + 255) / 256, 256, 0, stream>>>(x, xb, NN * IN_C);
  WtArgs wa;
  wa.W[0] = W1l; wa.Wt[0] = W1lt; wa.K[0] = IN_C;  wa.N[0] = HID_C;
  wa.W[1] = W1r; wa.Wt[1] = W1rt; wa.K[1] = IN_C;  wa.N[1] = HID_C;
  wa.W[2] = W2l; wa.Wt[2] = W2lt; wa.K[2] = HID_C; wa.N[2] = HID_C;
  wa.W[3] = W2r; wa.Wt[3] = W2rt; wa.K[3] = HID_C; wa.N[3] = HID_C;
  wa.W[4] = Wcl; wa.Wt[4] = Wc3t;             wa.K[4] = HID_C; wa.N[4] = OUT_C;
  wa.W[5] = Wcr; wa.Wt[5] = Wc3t + 64 * 256;  wa.K[5] = HID_C; wa.N[5] = OUT_C;
  wa.off[0] = 0;
  for (int s = 0; s < 6; ++s) wa.off[s + 1] = wa.off[s] + wa.K[s] * wa.N[s];
  wt_all_k<<<(wa.off[6] + 255) / 256, 256, 0, stream>>>(wa);

  // CSR build (bucketed two-phase sort)
  detect_edge_k<<<1, 256, 0, stream>>>(ei, eflag);
  bcount_k<<<K3_BLOCKS, 256, 0, stream>>>(ei, eflag, bcnt);
  bscan_k<<<1, 512, 0, stream>>>(bcnt, bbase);
  bscatter_k<<<K3_BLOCKS, 256, 0, stream>>>(ei, eflag, bbase, bfill, pairs);
  bsort_k<<<NB, 256, 0, stream>>>(pairs, bbase, rowptr, csr);

  int wb = (NN + 3) / 4;        // one wave per row/node kernels
  int mblocks = (NN + 127) / 128;

  // layer 1: quantize x (s8 per-row), agg, dual GEMM -> h1 (BN+ReLU)
  quant_k<IN_C, true, float><<<wb, 256, 0, stream>>>(x, xq, scx);
  agg_q8_k<IN_C, true><<<wb, 256, 0, stream>>>(xq, scx, rowptr, csr, aggb);
  dim3 g1d(mblocks, HID_C / 128);
  mfma_gemm_k<IN_C><<<g1d, 256, 0, stream>>>(
      aggb, xb, W1lt, W1rt, b1l, g1, be1, rm1, rv1, h1, NN, HID_C);

  // layer 2: quantize h1 (u8 per-row, post-ReLU), agg, dual GEMM -> h2 (BN+ReLU)
  quant_k<HID_C, false, bf16_t><<<wb, 256, 0, stream>>>(h1, h1q, sc1);
  agg_q8_k<HID_C, false><<<wb, 256, 0, stream>>>(h1q, sc1, rowptr, csr, aggb);
  mfma_gemm_k<HID_C><<<g1d, 256, 0, stream>>>(
      aggb, h1, W2lt, W2rt, b2l, g2, be2, rm2, rv2, h2, NN, HID_C);

  // layer 3 (linearity-reordered): P = h2@Wcl, Q = h2@Wcr + bcl; out = agg(P) + Q
  gemm3_k<<<mblocks, 256, 0, stream>>>(h2, Wc3t, bcl, P, Q, NN);
  quant_k<OUT_C, true, bf16_t><<<wb, 256, 0, stream>>>(P, Pq, scp);
  agg_final_q8_k<<<wb, 256, 0, stream>>>(Pq, scp, Q, rowptr, csr, (float*)d_out);
}

// Round 3
// 614.171 us; speedup vs baseline: 1.0494x; 1.0494x over previous
//
#include <hip/hip_runtime.h>
#include <stdint.h>

#define NN 100000
#define EE 1600000
#define IN_C 128
#define HID_C 256
#define OUT_C 64

#define NB 391            // CSR buckets: 256 node-ids each (391*256 = 100096 >= NN)
#define CAP 5120          // LDS sort capacity per bucket (expected 4096, +16 sigma)
#define K3_NPT 25         // edges per thread in bucket kernels
#define K3_BLOCKS 250     // 250 * 256 * 25 = 1.6M = EE exactly

typedef unsigned short bf16_t;
typedef unsigned int u32;
typedef __attribute__((ext_vector_type(8))) short bf16x8;
typedef __attribute__((ext_vector_type(4))) float f32x4;

__device__ __forceinline__ float b2f(unsigned short u){
  unsigned int x = ((unsigned int)u) << 16;
  return __uint_as_float(x);
}
__device__ __forceinline__ unsigned short f2b(float f){
  unsigned int x = __float_as_uint(f);
  unsigned int r = x + 0x7FFFu + ((x >> 16) & 1u);   // RNE
  return (unsigned short)(r >> 16);
}

// async global->LDS, 16B per lane. LDS dest is wave-uniform base + lane*16.
#define GL16(gp, lp) __builtin_amdgcn_global_load_lds( \
    (const __attribute__((address_space(1))) void*)(gp), \
    (__attribute__((address_space(3))) void*)(lp), 16, 0, 0)

// ---------------- edge dtype detector ----------------
__global__ void detect_edge_k(const int* __restrict__ ei, int* __restrict__ eflag){
  __shared__ int sm[256];
  int t = threadIdx.x;
  int o = 0;
  for (int i = t; i < 1024; i += 256) o |= ei[2*i + 1];
  sm[t] = o; __syncthreads();
  for (int s = 128; s > 0; s >>= 1){
    if (t < s) sm[t] |= sm[t + s];
    __syncthreads();
  }
  if (t == 0) *eflag = (sm[0] == 0) ? 1 : 0;   // 1 = int64 layout
}

// ---------------- CSR build: bucketed two-phase sort ----------------
// K1: per-bucket edge counts (LDS histogram, few global atomics)
__global__ __launch_bounds__(256) void bcount_k(const int* __restrict__ ei,
    const int* __restrict__ eflag, int* __restrict__ bcnt){
  __shared__ int h[NB];
  int t = threadIdx.x;
  for (int i = t; i < NB; i += 256) h[i] = 0;
  __syncthreads();
  int i64 = *eflag;
  int base = blockIdx.x * (256 * K3_NPT);
  #pragma unroll
  for (int q = 0; q < K3_NPT; ++q){
    int e = base + q * 256 + t;
    int d = i64 ? ei[2*(EE + e)] : ei[EE + e];
    atomicAdd(&h[d >> 8], 1);
  }
  __syncthreads();
  for (int i = t; i < NB; i += 256) if (h[i]) atomicAdd(&bcnt[i], h[i]);
}

// K2: exclusive scan of bucket counts -> bbase[0..NB]
__global__ void bscan_k(const int* __restrict__ bcnt, int* __restrict__ bbase){
  __shared__ int sm[512];
  int t = threadIdx.x;
  sm[t] = (t < NB) ? bcnt[t] : 0;
  __syncthreads();
  for (int off = 1; off < 512; off <<= 1){
    int a = (t >= off) ? sm[t - off] : 0;
    __syncthreads();
    sm[t] += a;
    __syncthreads();
  }
  if (t <= NB) bbase[t] = (t == 0) ? 0 : sm[t - 1];
}

// K3: scatter (src,dst) into bucket-grouped pairs with per-(block,bucket)
// reservations -> writes are sequential runs (L2 line-merge friendly)
__global__ __launch_bounds__(256) void bscatter_k(const int* __restrict__ ei,
    const int* __restrict__ eflag, const int* __restrict__ bbase,
    int* __restrict__ bfill, uint2* __restrict__ pairs){
  __shared__ int cnt[NB];
  __shared__ int cnt2[NB];
  __shared__ int lbase[NB];
  int t = threadIdx.x;
  for (int i = t; i < NB; i += 256){ cnt[i] = 0; cnt2[i] = 0; }
  __syncthreads();
  int i64 = *eflag;
  int ebase = blockIdx.x * (256 * K3_NPT);
  int src[K3_NPT], dst[K3_NPT];
  #pragma unroll
  for (int q = 0; q < K3_NPT; ++q){
    int e = ebase + q * 256 + t;
    src[q] = i64 ? ei[2*e] : ei[e];
    dst[q] = i64 ? ei[2*(EE + e)] : ei[EE + e];
    atomicAdd(&cnt[dst[q] >> 8], 1);
  }
  __syncthreads();
  for (int i = t; i < NB; i += 256)
    lbase[i] = cnt[i] ? atomicAdd(&bfill[i], cnt[i]) : 0;
  __syncthreads();
  #pragma unroll
  for (int q = 0; q < K3_NPT; ++q){
    int b = dst[q] >> 8;
    int r = atomicAdd(&cnt2[b], 1);
    pairs[bbase[b] + lbase[b] + r] = make_uint2((u32)src[q], (u32)dst[q]);
  }
}

// K4: per-bucket counting sort in LDS -> coalesced csr + rowptr writes
__global__ __launch_bounds__(256) void bsort_k(const uint2* __restrict__ pairs,
    const int* __restrict__ bbase, int* __restrict__ rowptr, int* __restrict__ csr){
  __shared__ int hist[256];
  __shared__ int pref[257];
  __shared__ int cnt[256];
  __shared__ int lsrc[CAP];
  int b = blockIdx.x;
  int t = threadIdx.x;
  int e0 = bbase[b], e1 = bbase[b + 1];
  int s = e1 - e0;
  hist[t] = 0; cnt[t] = 0;
  __syncthreads();
  for (int i = t; i < s; i += 256)
    atomicAdd(&hist[pairs[e0 + i].y & 255], 1);
  __syncthreads();
  // inclusive scan of hist
  for (int off = 1; off < 256; off <<= 1){
    int a = (t >= off) ? hist[t - off] : 0;
    __syncthreads();
    hist[t] += a;
    __syncthreads();
  }
  if (t == 0) pref[0] = 0;
  pref[t + 1] = hist[t];
  __syncthreads();
  // rowptr: global node id = b*256 + t (guard <= NN; bucket b+1 rewrites its own base)
  int gid = b * 256 + t;
  if (gid <= NN) rowptr[gid] = e0 + pref[t];
  // counting-sort scatter into LDS (spill path for oversized buckets)
  for (int i = t; i < s; i += 256){
    uint2 p = pairs[e0 + i];
    int bin = p.y & 255;
    int r = atomicAdd(&cnt[bin], 1);
    int pos = pref[bin] + r;
    if (pos < CAP) lsrc[pos] = (int)p.x;
    else           csr[e0 + pos] = (int)p.x;
  }
  __syncthreads();
  int lim = s < CAP ? s : CAP;
  for (int i = t; i < lim; i += 256) csr[e0 + i] = lsrc[i];
}

// ---------------- dtype conversion ----------------

__global__ void f2b_vec_k(const float* __restrict__ in, bf16_t* __restrict__ out, int n){
  int g = blockIdx.x * 256 + threadIdx.x;
  int i = g * 4;
  if (i < n){
    float4 v = *(const float4*)(in + i);
    uint2 u;
    u.x = (u32)f2b(v.x) | ((u32)f2b(v.y) << 16);
    u.y = (u32)f2b(v.z) | ((u32)f2b(v.w) << 16);
    *(uint2*)(out + i) = u;
  }
}

struct WtArgs {
  const float* W[6];
  bf16_t* Wt[6];
  int K[6], N[6];
  int off[7];
};

__global__ void wt_all_k(WtArgs a){
  int g = blockIdx.x * 256 + threadIdx.x;
  if (g >= a.off[6]) return;
  #pragma unroll
  for (int s = 0; s < 6; ++s){
    if (g >= a.off[s] && g < a.off[s + 1]){
      int local = g - a.off[s];
      int K = a.K[s], N = a.N[s];
      int n = local / K, k = local - n * K;
      a.Wt[s][local] = f2b(a.W[s][(size_t)k * N + n]);
    }
  }
}

// ---------------- per-row quantization: one wave per row ----------------

template<int C, bool SIGNED, typename TIN>
__global__ __launch_bounds__(256) void quant_k(const TIN* __restrict__ in,
    uint8_t* __restrict__ outq, float* __restrict__ scales){
  constexpr int V = C / 64;
  int row  = (blockIdx.x * 256 + threadIdx.x) >> 6;
  int lane = threadIdx.x & 63;
  if (row >= NN) return;
  float v[V];
  if constexpr (sizeof(TIN) == 4){
    float2 u = *(const float2*)((const float*)in + (size_t)row * C + lane * 2);
    v[0] = u.x; v[1] = u.y;
  } else {
    const bf16_t* bp = (const bf16_t*)in + (size_t)row * C + lane * V;
    if constexpr (V == 4){
      uint2 u = *(const uint2*)bp;
      v[0] = b2f((unsigned short)(u.x & 0xffffu)); v[1] = b2f((unsigned short)(u.x >> 16));
      v[2] = b2f((unsigned short)(u.y & 0xffffu)); v[3] = b2f((unsigned short)(u.y >> 16));
    } else if constexpr (V == 2){
      u32 u = *(const u32*)bp;
      v[0] = b2f((unsigned short)(u & 0xffffu)); v[1] = b2f((unsigned short)(u >> 16));
    } else {
      v[0] = b2f(*bp);
    }
  }
  float m = 0.f;
  #pragma unroll
  for (int i = 0; i < V; ++i) m = fmaxf(m, SIGNED ? fabsf(v[i]) : v[i]);
  #pragma unroll
  for (int msk = 1; msk < 64; msk <<= 1) m = fmaxf(m, __shfl_xor(m, msk, 64));
  const float qmax = SIGNED ? 127.f : 255.f;
  float inv = m > 0.f ? qmax / m : 0.f;
  uint8_t qb[V];
  #pragma unroll
  for (int i = 0; i < V; ++i){
    float qf = rintf(v[i] * inv);
    if (SIGNED){
      qf = fminf(fmaxf(qf, -127.f), 127.f);
      qb[i] = (uint8_t)(int8_t)(int)qf;
    } else {
      qf = fminf(fmaxf(qf, 0.f), 255.f);
      qb[i] = (uint8_t)(int)qf;
    }
  }
  uint8_t* op = outq + (size_t)row * C + lane * V;
  if constexpr (V == 4){
    u32 p = (u32)qb[0] | ((u32)qb[1] << 8) | ((u32)qb[2] << 16) | ((u32)qb[3] << 24);
    *(u32*)op = p;
  } else if constexpr (V == 2){
    *(unsigned short*)op = (unsigned short)((u32)qb[0] | ((u32)qb[1] << 8));
  } else {
    *op = qb[0];
  }
  if (lane == 0) scales[row] = m / qmax;
}

// ---------------- mean aggregation over quantized rows ----------------
// VMEM-issue-optimized packed gather: each lane loads 16B (uint4), so one
// wave-wide load covers G = 64/(C/16) edges at once (4 for C=256, 8 for
// C=128). Per-lane f32 acc over 16 columns; cross-edge-group merge via
// __shfl_xor tree at the end. 4-8x fewer VMEM instructions than 4B/lane.

template<int C, bool SIGNED>
__global__ __launch_bounds__(256) void agg_q8_k(const uint8_t* __restrict__ tq,
    const float* __restrict__ tsc,
    const int* __restrict__ rowptr, const int* __restrict__ csr,
    bf16_t* __restrict__ outm){
  constexpr int L = C / 16;        // lanes per edge
  constexpr int G = 64 / L;        // edges per wave-instruction
  int wid  = (blockIdx.x * 256 + threadIdx.x) >> 6;
  int lane = threadIdx.x & 63;
  if (wid >= NN) return;
  int beg = __builtin_amdgcn_readfirstlane(rowptr[wid]);
  int end = __builtin_amdgcn_readfirstlane(rowptr[wid + 1]);
  int g = lane / L;                // edge slot within group
  int r = lane % L;                // 16B slice within row

  float acc[16];
  #pragma unroll
  for (int i = 0; i < 16; ++i) acc[i] = 0.f;

  int last = end - 1;
  for (int e = beg; e < end; e += G){
    int idx = e + g;
    int cl  = idx < last ? idx : last;      // clamp (same-line dup, scale 0)
    int s_  = csr[cl];
    float sv = tsc[s_];
    float sc = idx < end ? sv : 0.f;
    uint4 w = *(const uint4*)(tq + (size_t)s_ * C + r * 16);
    u32 ws[4] = {w.x, w.y, w.z, w.w};
    #pragma unroll
    for (int b = 0; b < 4; ++b)
      #pragma unroll
      for (int j = 0; j < 4; ++j){
        u32 byte = (ws[b] >> (8 * j)) & 0xffu;
        float v = SIGNED ? (float)(int)(int8_t)(uint8_t)byte : (float)byte;
        acc[b * 4 + j] += sc * v;
      }
  }

  // merge the G edge-groups (lanes differing in bits >= log2(L))
  #pragma unroll
  for (int mask = L; mask < 64; mask <<= 1)
    #pragma unroll
    for (int i = 0; i < 16; ++i)
      acc[i] += __shfl_xor(acc[i], mask, 64);

  int d = end - beg;
  float di = d > 0 ? 1.0f / (float)d : 0.f;
  if (lane < L){
    bf16_t* po = outm + (size_t)wid * C + lane * 16;
    u32 o[8];
    #pragma unroll
    for (int i = 0; i < 8; ++i)
      o[i] = (u32)f2b(acc[2 * i] * di) | ((u32)f2b(acc[2 * i + 1] * di) << 16);
    *(uint4*)(po)     = make_uint4(o[0], o[1], o[2], o[3]);
    *(uint4*)(po + 8) = make_uint4(o[4], o[5], o[6], o[7]);
  }
}

// ---------------- final aggregation (layer 3, C=64, int8 P) ----------------
// Same packed-gather structure: 4 lanes/edge, 16 edges per wave-instruction.

__global__ __launch_bounds__(256) void agg_final_q8_k(
    const uint8_t* __restrict__ Pq, const float* __restrict__ scp,
    const float* __restrict__ Q,
    const int* __restrict__ rowptr, const int* __restrict__ csr,
    float* __restrict__ out){
  constexpr int L = 4, G = 16;
  int wid  = (blockIdx.x * 256 + threadIdx.x) >> 6;
  int lane = threadIdx.x & 63;
  if (wid >= NN) return;
  int beg = __builtin_amdgcn_readfirstlane(rowptr[wid]);
  int end = __builtin_amdgcn_readfirstlane(rowptr[wid + 1]);
  int g = lane >> 2;
  int r = lane & 3;

  float acc[16];
  #pragma unroll
  for (int i = 0; i < 16; ++i) acc[i] = 0.f;

  int last = end - 1;
  for (int e = beg; e < end; e += G){
    int idx = e + g;
    int cl  = idx < last ? idx : last;
    int s_  = csr[cl];
    float sv = scp[s_];
    float sc = idx < end ? sv : 0.f;
    uint4 w = *(const uint4*)(Pq + (size_t)s_ * 64 + r * 16);
    u32 ws[4] = {w.x, w.y, w.z, w.w};
    #pragma unroll
    for (int b = 0; b < 4; ++b)
      #pragma unroll
      for (int j = 0; j < 4; ++j){
        u32 byte = (ws[b] >> (8 * j)) & 0xffu;
        acc[b * 4 + j] += sc * (float)(int)(int8_t)(uint8_t)byte;
      }
  }

  #pragma unroll
  for (int mask = L; mask < 64; mask <<= 1)
    #pragma unroll
    for (int i = 0; i < 16; ++i)
      acc[i] += __shfl_xor(acc[i], mask, 64);

  int d = end - beg;
  float di = d > 0 ? 1.0f / (float)d : 0.f;
  if (lane < L){
    float* po = out + (size_t)wid * 64 + lane * 16;
    const float* qo = Q + (size_t)wid * 64 + lane * 16;
    #pragma unroll
    for (int i = 0; i < 16; ++i)
      po[i] = acc[i] * di + qo[i];
  }
}

// ---------------- MFMA dual-GEMM + bias + BN + ReLU (layers 1,2) ----------------
// 2-phase pipeline: global_load_lds(16B) staging into XOR-swizzled linear LDS,
// double-buffered, counted s_waitcnt vmcnt(8) (never drained mid-loop),
// raw s_barrier (no compiler vmcnt(0) drain).
// LDS layout: chunk c (16B) at offset c*16, c = row*8 + slot, slot = k8 ^ (row&7).
// Staging inverse-swizzles the *global* source so reads swizzle symmetrically.

template<int K_>
__global__ __launch_bounds__(256) void mfma_gemm_k(
    const bf16_t* __restrict__ A0, const bf16_t* __restrict__ A1,
    const bf16_t* __restrict__ W0t, const bf16_t* __restrict__ W1t,
    const float* __restrict__ bias,
    const float* __restrict__ gamma, const float* __restrict__ beta,
    const float* __restrict__ rmean, const float* __restrict__ rvar,
    bf16_t* __restrict__ out, int M, int Nout)
{
  constexpr int BM = 128;
  constexpr int BN = 128;
  constexpr int BK = 64;
  constexpr int KT = K_ / BK;     // k-tiles per pass
  constexpr int T  = 2 * KT;      // total tiles across both passes
  __shared__ bf16_t As[2][BM * BK];
  __shared__ bf16_t Bs[2][BN * BK];

  int t    = threadIdx.x;
  int lane = t & 63;
  int wid  = t >> 6;
  int wr   = wid >> 1, wc = wid & 1;
  int l15  = lane & 15;
  int quad = lane >> 4;

  int m0 = blockIdx.x * BM;
  int n0 = blockIdx.y * BN;

  f32x4 acc[4][4];
  #pragma unroll
  for (int i = 0; i < 4; ++i)
    #pragma unroll
    for (int j = 0; j < 4; ++j)
      acc[i][j] = (f32x4){0.f, 0.f, 0.f, 0.f};

  auto stage = [&](int tile, int buf){
    const bf16_t* Ap = (tile < KT) ? A0 : A1;
    const bf16_t* Wp = (tile < KT) ? W0t : W1t;
    int k0 = ((tile < KT) ? tile : tile - KT) * BK;
    #pragma unroll
    for (int i = 0; i < 4; ++i){           // A: 1024 chunks, 4 gload/wave
      int c   = i * 256 + t;
      int row = c >> 3;
      int k8  = (c & 7) ^ (row & 7);
      int gm  = m0 + row; gm = gm < NN ? gm : NN - 1;
      GL16(Ap + (size_t)gm * K_ + k0 + k8 * 8, &As[buf][(i * 256 + (t & 192)) * 8]);
    }
    #pragma unroll
    for (int i = 0; i < 4; ++i){           // B: 1024 chunks, 4 gload/wave
      int c   = i * 256 + t;
      int row = c >> 3;
      int k8  = (c & 7) ^ (row & 7);
      GL16(Wp + (size_t)(n0 + row) * K_ + k0 + k8 * 8, &Bs[buf][(i * 256 + (t & 192)) * 8]);
    }
  };

  stage(0, 0);
  #pragma unroll
  for (int tile = 0; tile < T; ++tile){
    int buf = tile & 1;
    if (tile + 1 < T){
      stage(tile + 1, buf ^ 1);                        // issue next, no wait
      asm volatile("s_waitcnt vmcnt(8)" ::: "memory"); // current tile's 8 landed
    } else {
      asm volatile("s_waitcnt vmcnt(0)" ::: "memory");
    }
    __builtin_amdgcn_s_barrier();                      // all waves' chunks visible
    #pragma unroll
    for (int kk = 0; kk < 2; ++kk){
      bf16x8 af[4], bfr[4];
      #pragma unroll
      for (int i = 0; i < 4; ++i){
        int row = wr * 64 + i * 16 + l15;
        af[i] = *(const bf16x8*)(&As[buf][(size_t)((row << 3) + ((quad + kk * 4) ^ (row & 7))) * 8]);
      }
      #pragma unroll
      for (int j = 0; j < 4; ++j){
        int row = wc * 64 + j * 16 + l15;
        bfr[j] = *(const bf16x8*)(&Bs[buf][(size_t)((row << 3) + ((quad + kk * 4) ^ (row & 7))) * 8]);
      }
      #pragma unroll
      for (int i = 0; i < 4; ++i)
        #pragma unroll
        for (int j = 0; j < 4; ++j)
          acc[i][j] = __builtin_amdgcn_mfma_f32_16x16x32_bf16(af[i], bfr[j], acc[i][j], 0, 0, 0);
    }
    __builtin_amdgcn_s_barrier();                      // protect buf before overwrite
  }

  #pragma unroll
  for (int j = 0; j < 4; ++j){
    int col = n0 + wc * 64 + j * 16 + l15;
    float sc = gamma[col] * rsqrtf(rvar[col] + 1e-5f);
    float shift = (bias[col] - rmean[col]) * sc + beta[col];
    #pragma unroll
    for (int i = 0; i < 4; ++i){
      int rbase = m0 + wr * 64 + i * 16 + quad * 4;
      #pragma unroll
      for (int r = 0; r < 4; ++r){
        int row = rbase + r;
        if (row < M){
          float v = fmaxf(acc[i][j][r] * sc + shift, 0.f);
          out[(size_t)row * Nout + col] = f2b(v);
        }
      }
    }
  }
}

// ---------------- layer-3 single-A GEMM: P = A@Wcl (bf16), Q = A@Wcr + bcl (f32) ----------------
// Same 2-phase global_load_lds pipeline, single pass, K=256.

__global__ __launch_bounds__(256) void gemm3_k(
    const bf16_t* __restrict__ A, const bf16_t* __restrict__ Wt,
    const float* __restrict__ bcl,
    bf16_t* __restrict__ P, float* __restrict__ Q, int M)
{
  constexpr int K_ = 256, BM = 128, BN = 128, BK = 64;
  constexpr int T = K_ / BK;      // 4 tiles
  __shared__ bf16_t As[2][BM * BK];
  __shared__ bf16_t Bs[2][BN * BK];

  int t    = threadIdx.x;
  int lane = t & 63;
  int wid  = t >> 6;
  int wr   = wid >> 1, wc = wid & 1;
  int l15  = lane & 15;
  int quad = lane >> 4;
  int m0 = blockIdx.x * BM;

  f32x4 acc[4][4];
  #pragma unroll
  for (int i = 0; i < 4; ++i)
    #pragma unroll
    for (int j = 0; j < 4; ++j)
      acc[i][j] = (f32x4){0.f, 0.f, 0.f, 0.f};

  auto stage = [&](int tile, int buf){
    int k0 = tile * BK;
    #pragma unroll
    for (int i = 0; i < 4; ++i){
      int c   = i * 256 + t;
      int row = c >> 3;
      int k8  = (c & 7) ^ (row & 7);
      int gm  = m0 + row; gm = gm < NN ? gm : NN - 1;
      GL16(A + (size_t)gm * K_ + k0 + k8 * 8, &As[buf][(i * 256 + (t & 192)) * 8]);
    }
    #pragma unroll
    for (int i = 0; i < 4; ++i){
      int c   = i * 256 + t;
      int row = c >> 3;
      int k8  = (c & 7) ^ (row & 7);
      GL16(Wt + (size_t)row * K_ + k0 + k8 * 8, &Bs[buf][(i * 256 + (t & 192)) * 8]);
    }
  };

  stage(0, 0);
  #pragma unroll
  for (int tile = 0; tile < T; ++tile){
    int buf = tile & 1;
    if (tile + 1 < T){
      stage(tile + 1, buf ^ 1);
      asm volatile("s_waitcnt vmcnt(8)" ::: "memory");
    } else {
      asm volatile("s_waitcnt vmcnt(0)" ::: "memory");
    }
    __builtin_amdgcn_s_barrier();
    #pragma unroll
    for (int kk = 0; kk < 2; ++kk){
      bf16x8 af[4], bfr[4];
      #pragma unroll
      for (int i = 0; i < 4; ++i){
        int row = wr * 64 + i * 16 + l15;
        af[i] = *(const bf16x8*)(&As[buf][(size_t)((row << 3) + ((quad + kk * 4) ^ (row & 7))) * 8]);
      }
      #pragma unroll
      for (int j = 0; j < 4; ++j){
        int row = wc * 64 + j * 16 + l15;
        bfr[j] = *(const bf16x8*)(&Bs[buf][(size_t)((row << 3) + ((quad + kk * 4) ^ (row & 7))) * 8]);
      }
      #pragma unroll
      for (int i = 0; i < 4; ++i)
        #pragma unroll
        for (int j = 0; j < 4; ++j)
          acc[i][j] = __builtin_amdgcn_mfma_f32_16x16x32_bf16(af[i], bfr[j], acc[i][j], 0, 0, 0);
    }
    __builtin_amdgcn_s_barrier();
  }

  #pragma unroll
  for (int j = 0; j < 4; ++j){
    int col = wc * 64 + j * 16 + l15;      // 0..127
    #pragma unroll
    for (int i = 0; i < 4; ++i){
      int rbase = m0 + wr * 64 + i * 16 + quad * 4;
      #pragma unroll
      for (int r = 0; r < 4; ++r){
        int row = rbase + r;
        if (row < M){
          float v = acc[i][j][r];
          if (col < 64) P[(size_t)row * 64 + col] = f2b(v);
          else          Q[(size_t)row * 64 + (col - 64)] = v + bcl[col - 64];
        }
      }
    }
  }
}

// ---------------- launch ----------------

extern "C" void kernel_launch(void* const* d_in, const int* in_sizes, int n_in,
                              void* d_out, int out_size, void* d_ws, size_t ws_size,
                              hipStream_t stream)
{
  const float* x   = (const float*)d_in[0];
  const int*   ei  = (const int*)d_in[1];
  const float* W1l = (const float*)d_in[2];
  const float* b1l = (const float*)d_in[3];
  const float* W1r = (const float*)d_in[4];
  const float* g1  = (const float*)d_in[5];
  const float* be1 = (const float*)d_in[6];
  const float* rm1 = (const float*)d_in[7];
  const float* rv1 = (const float*)d_in[8];
  const float* W2l = (const float*)d_in[9];
  const float* b2l = (const float*)d_in[10];
  const float* W2r = (const float*)d_in[11];
  const float* g2  = (const float*)d_in[12];
  const float* be2 = (const float*)d_in[13];
  const float* rm2 = (const float*)d_in[14];
  const float* rv2 = (const float*)d_in[15];
  const float* Wcl = (const float*)d_in[16];
  const float* bcl = (const float*)d_in[17];
  const float* Wcr = (const float*)d_in[18];
  (void)in_sizes; (void)n_in; (void)out_size; (void)ws_size;

  char* ws = (char*)d_ws;
  size_t off = 0;
  auto alloc = [&](size_t bytes)->char* {
    char* p = ws + off;
    off += (bytes + 15) & ~(size_t)15;
    return p;
  };
  int*    bcnt   = (int*)   alloc(800 * 4);             // [NB] counts + [NB] fill (contig)
  int*    bfill  = bcnt + 400;
  int*    bbase  = (int*)   alloc((size_t)(NB + 1) * 4);
  int*    rowptr = (int*)   alloc((size_t)(NN + 1) * 4);
  int*    eflag  = (int*)   alloc(16);
  int*    csr    = (int*)   alloc((size_t)EE * 4);
  bf16_t* xb     = (bf16_t*)alloc((size_t)NN * IN_C * 2);
  bf16_t* aggb   = (bf16_t*)alloc((size_t)NN * HID_C * 2);
  bf16_t* h1     = (bf16_t*)alloc((size_t)NN * HID_C * 2);
  bf16_t* h2     = (bf16_t*)alloc((size_t)NN * HID_C * 2);
  bf16_t* W1lt   = (bf16_t*)alloc((size_t)IN_C  * HID_C * 2);
  bf16_t* W1rt   = (bf16_t*)alloc((size_t)IN_C  * HID_C * 2);
  bf16_t* W2lt   = (bf16_t*)alloc((size_t)HID_C * HID_C * 2);
  bf16_t* W2rt   = (bf16_t*)alloc((size_t)HID_C * HID_C * 2);
  bf16_t* Wc3t   = (bf16_t*)alloc((size_t)128 * HID_C * 2);  // [128][256] concat
  float*  sc1    = (float*) alloc((size_t)NN * 4);           // h1 row scales
  float*  scp    = (float*) alloc((size_t)NN * 4);           // P row scales

  // aliases into dead-by-then regions:
  uint2*   pairs = (uint2*)aggb;                     // [E] (src,dst), CSR build only
  uint8_t* xq  = (uint8_t*)h2;                       // [N,128] s8, dead before GEMM2 writes h2
  float*   scx = (float*)((char*)h2 + (size_t)NN * IN_C);
  uint8_t* h1q = (uint8_t*)xb;                       // [N,256] u8, xb dead after GEMM1
  bf16_t*  P   = xb;                                 // [N,64] bf16, h1q dead after layer-2 agg
  uint8_t* Pq  = (uint8_t*)aggb;                     // [N,64] s8, aggb dead after GEMM2
  float*   Q   = (float*)h1;                         // [N,64] f32, h1 dead after GEMM2

  hipMemsetAsync(bcnt, 0, 800 * 4, stream);

  // conversions
  f2b_vec_k<<<(NN * IN_C / 4 + 255) / 256, 256, 0, stream>>>(x, xb, NN * IN_C);
  WtArgs wa;
  wa.W[0] = W1l; wa.Wt[0] = W1lt; wa.K[0] = IN_C;  wa.N[0] = HID_C;
  wa.W[1] = W1r; wa.Wt[1] = W1rt; wa.K[1] = IN_C;  wa.N[1] = HID_C;
  wa.W[2] = W2l; wa.Wt[2] = W2lt; wa.K[2] = HID_C; wa.N[2] = HID_C;
  wa.W[3] = W2r; wa.Wt[3] = W2rt; wa.K[3] = HID_C; wa.N[3] = HID_C;
  wa.W[4] = Wcl; wa.Wt[4] = Wc3t;             wa.K[4] = HID_C; wa.N[4] = OUT_C;
  wa.W[5] = Wcr; wa.Wt[5] = Wc3t + 64 * 256;  wa.K[5] = HID_C; wa.N[5] = OUT_C;
  wa.off[0] = 0;
  for (int s = 0; s < 6; ++s) wa.off[s + 1] = wa.off[s] + wa.K[s] * wa.N[s];
  wt_all_k<<<(wa.off[6] + 255) / 256, 256, 0, stream>>>(wa);

  // CSR build (bucketed two-phase sort)
  detect_edge_k<<<1, 256, 0, stream>>>(ei, eflag);
  bcount_k<<<K3_BLOCKS, 256, 0, stream>>>(ei, eflag, bcnt);
  bscan_k<<<1, 512, 0, stream>>>(bcnt, bbase);
  bscatter_k<<<K3_BLOCKS, 256, 0, stream>>>(ei, eflag, bbase, bfill, pairs);
  bsort_k<<<NB, 256, 0, stream>>>(pairs, bbase, rowptr, csr);

  int wb = (NN + 3) / 4;        // one wave per row/node kernels
  int mblocks = (NN + 127) / 128;

  // layer 1: quantize x (s8 per-row), agg, dual GEMM -> h1 (BN+ReLU)
  quant_k<IN_C, true, float><<<wb, 256, 0, stream>>>(x, xq, scx);
  agg_q8_k<IN_C, true><<<wb, 256, 0, stream>>>(xq, scx, rowptr, csr, aggb);
  dim3 g1d(mblocks, HID_C / 128);
  mfma_gemm_k<IN_C><<<g1d, 256, 0, stream>>>(
      aggb, xb, W1lt, W1rt, b1l, g1, be1, rm1, rv1, h1, NN, HID_C);

  // layer 2: quantize h1 (u8 per-row, post-ReLU), agg, dual GEMM -> h2 (BN+ReLU)
  quant_k<HID_C, false, bf16_t><<<wb, 256, 0, stream>>>(h1, h1q, sc1);
  agg_q8_k<HID_C, false><<<wb, 256, 0, stream>>>(h1q, sc1, rowptr, csr, aggb);
  mfma_gemm_k<HID_C><<<g1d, 256, 0, stream>>>(
      aggb, h1, W2lt, W2rt, b2l, g2, be2, rm2, rv2, h2, NN, HID_C);

  // layer 3 (linearity-reordered): P = h2@Wcl, Q = h2@Wcr + bcl; out = agg(P) + Q
  gemm3_k<<<mblocks, 256, 0, stream>>>(h2, Wc3t, bcl, P, Q, NN);
  quant_k<OUT_C, true, bf16_t><<<wb, 256, 0, stream>>>(P, Pq, scp);
  agg_final_q8_k<<<wb, 256, 0, stream>>>(Pq, scp, Q, rowptr, csr, (float*)d_out);
}

// Round 4
// 566.704 us; speedup vs baseline: 1.1373x; 1.0838x over previous
//
#include <hip/hip_runtime.h>
#include <stdint.h>

#define NN 100000
#define EE 1600000
#define IN_C 128
#define HID_C 256
#define OUT_C 64

#define NB 391            // CSR buckets: 256 node-ids each (391*256 = 100096 >= NN)
#define CAP 5120          // LDS sort capacity per bucket (expected 4096, +16 sigma)
#define K3_NPT 25         // edges per thread in bucket kernels
#define K3_BLOCKS 250     // 250 * 256 * 25 = 1.6M = EE exactly

typedef unsigned short bf16_t;
typedef unsigned int u32;
typedef __attribute__((ext_vector_type(8))) short bf16x8;
typedef __attribute__((ext_vector_type(4))) float f32x4;

__device__ __forceinline__ float b2f(unsigned short u){
  unsigned int x = ((unsigned int)u) << 16;
  return __uint_as_float(x);
}
__device__ __forceinline__ unsigned short f2b(float f){
  unsigned int x = __float_as_uint(f);
  unsigned int r = x + 0x7FFFu + ((x >> 16) & 1u);   // RNE
  return (unsigned short)(r >> 16);
}

// async global->LDS, 16B per lane. LDS dest is wave-uniform base + lane*16.
#define GL16(gp, lp) __builtin_amdgcn_global_load_lds( \
    (const __attribute__((address_space(1))) void*)(gp), \
    (__attribute__((address_space(3))) void*)(lp), 16, 0, 0)

// ---------------- edge dtype detector ----------------
__global__ void detect_edge_k(const int* __restrict__ ei, int* __restrict__ eflag){
  __shared__ int sm[256];
  int t = threadIdx.x;
  int o = 0;
  for (int i = t; i < 1024; i += 256) o |= ei[2*i + 1];
  sm[t] = o; __syncthreads();
  for (int s = 128; s > 0; s >>= 1){
    if (t < s) sm[t] |= sm[t + s];
    __syncthreads();
  }
  if (t == 0) *eflag = (sm[0] == 0) ? 1 : 0;   // 1 = int64 layout
}

// ---------------- CSR build: bucketed two-phase sort ----------------
// K1: per-bucket edge counts (LDS histogram, few global atomics)
__global__ __launch_bounds__(256) void bcount_k(const int* __restrict__ ei,
    const int* __restrict__ eflag, int* __restrict__ bcnt){
  __shared__ int h[NB];
  int t = threadIdx.x;
  for (int i = t; i < NB; i += 256) h[i] = 0;
  __syncthreads();
  int i64 = *eflag;
  int base = blockIdx.x * (256 * K3_NPT);
  #pragma unroll
  for (int q = 0; q < K3_NPT; ++q){
    int e = base + q * 256 + t;
    int d = i64 ? ei[2*(EE + e)] : ei[EE + e];
    atomicAdd(&h[d >> 8], 1);
  }
  __syncthreads();
  for (int i = t; i < NB; i += 256) if (h[i]) atomicAdd(&bcnt[i], h[i]);
}

// K2: exclusive scan of bucket counts -> bbase[0..NB]
__global__ void bscan_k(const int* __restrict__ bcnt, int* __restrict__ bbase){
  __shared__ int sm[512];
  int t = threadIdx.x;
  sm[t] = (t < NB) ? bcnt[t] : 0;
  __syncthreads();
  for (int off = 1; off < 512; off <<= 1){
    int a = (t >= off) ? sm[t - off] : 0;
    __syncthreads();
    sm[t] += a;
    __syncthreads();
  }
  if (t <= NB) bbase[t] = (t == 0) ? 0 : sm[t - 1];
}

// K3: scatter (src,dst) into bucket-grouped pairs with per-(block,bucket)
// reservations -> writes are sequential runs (L2 line-merge friendly)
__global__ __launch_bounds__(256) void bscatter_k(const int* __restrict__ ei,
    const int* __restrict__ eflag, const int* __restrict__ bbase,
    int* __restrict__ bfill, uint2* __restrict__ pairs){
  __shared__ int cnt[NB];
  __shared__ int cnt2[NB];
  __shared__ int lbase[NB];
  int t = threadIdx.x;
  for (int i = t; i < NB; i += 256){ cnt[i] = 0; cnt2[i] = 0; }
  __syncthreads();
  int i64 = *eflag;
  int ebase = blockIdx.x * (256 * K3_NPT);
  int src[K3_NPT], dst[K3_NPT];
  #pragma unroll
  for (int q = 0; q < K3_NPT; ++q){
    int e = ebase + q * 256 + t;
    src[q] = i64 ? ei[2*e] : ei[e];
    dst[q] = i64 ? ei[2*(EE + e)] : ei[EE + e];
    atomicAdd(&cnt[dst[q] >> 8], 1);
  }
  __syncthreads();
  for (int i = t; i < NB; i += 256)
    lbase[i] = cnt[i] ? atomicAdd(&bfill[i], cnt[i]) : 0;
  __syncthreads();
  #pragma unroll
  for (int q = 0; q < K3_NPT; ++q){
    int b = dst[q] >> 8;
    int r = atomicAdd(&cnt2[b], 1);
    pairs[bbase[b] + lbase[b] + r] = make_uint2((u32)src[q], (u32)dst[q]);
  }
}

// K4: per-bucket counting sort in LDS -> coalesced csr + rowptr writes
__global__ __launch_bounds__(256) void bsort_k(const uint2* __restrict__ pairs,
    const int* __restrict__ bbase, int* __restrict__ rowptr, int* __restrict__ csr){
  __shared__ int hist[256];
  __shared__ int pref[257];
  __shared__ int cnt[256];
  __shared__ int lsrc[CAP];
  int b = blockIdx.x;
  int t = threadIdx.x;
  int e0 = bbase[b], e1 = bbase[b + 1];
  int s = e1 - e0;
  hist[t] = 0; cnt[t] = 0;
  __syncthreads();
  for (int i = t; i < s; i += 256)
    atomicAdd(&hist[pairs[e0 + i].y & 255], 1);
  __syncthreads();
  // inclusive scan of hist
  for (int off = 1; off < 256; off <<= 1){
    int a = (t >= off) ? hist[t - off] : 0;
    __syncthreads();
    hist[t] += a;
    __syncthreads();
  }
  if (t == 0) pref[0] = 0;
  pref[t + 1] = hist[t];
  __syncthreads();
  // rowptr: global node id = b*256 + t (guard <= NN; bucket b+1 rewrites its own base)
  int gid = b * 256 + t;
  if (gid <= NN) rowptr[gid] = e0 + pref[t];
  // counting-sort scatter into LDS (spill path for oversized buckets)
  for (int i = t; i < s; i += 256){
    uint2 p = pairs[e0 + i];
    int bin = p.y & 255;
    int r = atomicAdd(&cnt[bin], 1);
    int pos = pref[bin] + r;
    if (pos < CAP) lsrc[pos] = (int)p.x;
    else           csr[e0 + pos] = (int)p.x;
  }
  __syncthreads();
  int lim = s < CAP ? s : CAP;
  for (int i = t; i < lim; i += 256) csr[e0 + i] = lsrc[i];
}

// ---------------- fused x convert + layer-1 quantize: one wave per row ----------------
// Reads x (f32) ONCE; emits xb (bf16) and xq (s8 per-row) + scale.

__global__ __launch_bounds__(256) void xconv_k(const float* __restrict__ x,
    bf16_t* __restrict__ xb, uint8_t* __restrict__ xq, float* __restrict__ scx){
  int row  = (blockIdx.x * 256 + threadIdx.x) >> 6;
  int lane = threadIdx.x & 63;
  if (row >= NN) return;
  float2 u = *(const float2*)(x + (size_t)row * IN_C + lane * 2);
  u32 bb = (u32)f2b(u.x) | ((u32)f2b(u.y) << 16);
  *(u32*)(xb + (size_t)row * IN_C + lane * 2) = bb;
  float m = fmaxf(fabsf(u.x), fabsf(u.y));
  #pragma unroll
  for (int msk = 1; msk < 64; msk <<= 1) m = fmaxf(m, __shfl_xor(m, msk, 64));
  float inv = m > 0.f ? 127.f / m : 0.f;
  float qa = fminf(fmaxf(rintf(u.x * inv), -127.f), 127.f);
  float qb = fminf(fmaxf(rintf(u.y * inv), -127.f), 127.f);
  u32 pa = (u32)(uint8_t)(int8_t)(int)qa | (((u32)(uint8_t)(int8_t)(int)qb) << 8);
  *(unsigned short*)(xq + (size_t)row * IN_C + lane * 2) = (unsigned short)pa;
  if (lane == 0) scx[row] = m / 127.f;
}

// ---------------- dtype conversion (weights) ----------------

struct WtArgs {
  const float* W[6];
  bf16_t* Wt[6];
  int K[6], N[6];
  int off[7];
};

__global__ void wt_all_k(WtArgs a){
  int g = blockIdx.x * 256 + threadIdx.x;
  if (g >= a.off[6]) return;
  #pragma unroll
  for (int s = 0; s < 6; ++s){
    if (g >= a.off[s] && g < a.off[s + 1]){
      int local = g - a.off[s];
      int K = a.K[s], N = a.N[s];
      int n = local / K, k = local - n * K;
      a.Wt[s][local] = f2b(a.W[s][(size_t)k * N + n]);
    }
  }
}

// ---------------- per-row quantization: one wave per row ----------------

template<int C, bool SIGNED, typename TIN>
__global__ __launch_bounds__(256) void quant_k(const TIN* __restrict__ in,
    uint8_t* __restrict__ outq, float* __restrict__ scales){
  constexpr int V = C / 64;
  int row  = (blockIdx.x * 256 + threadIdx.x) >> 6;
  int lane = threadIdx.x & 63;
  if (row >= NN) return;
  float v[V];
  if constexpr (sizeof(TIN) == 4){
    float2 u = *(const float2*)((const float*)in + (size_t)row * C + lane * 2);
    v[0] = u.x; v[1] = u.y;
  } else {
    const bf16_t* bp = (const bf16_t*)in + (size_t)row * C + lane * V;
    if constexpr (V == 4){
      uint2 u = *(const uint2*)bp;
      v[0] = b2f((unsigned short)(u.x & 0xffffu)); v[1] = b2f((unsigned short)(u.x >> 16));
      v[2] = b2f((unsigned short)(u.y & 0xffffu)); v[3] = b2f((unsigned short)(u.y >> 16));
    } else if constexpr (V == 2){
      u32 u = *(const u32*)bp;
      v[0] = b2f((unsigned short)(u & 0xffffu)); v[1] = b2f((unsigned short)(u >> 16));
    } else {
      v[0] = b2f(*bp);
    }
  }
  float m = 0.f;
  #pragma unroll
  for (int i = 0; i < V; ++i) m = fmaxf(m, SIGNED ? fabsf(v[i]) : v[i]);
  #pragma unroll
  for (int msk = 1; msk < 64; msk <<= 1) m = fmaxf(m, __shfl_xor(m, msk, 64));
  const float qmax = SIGNED ? 127.f : 255.f;
  float inv = m > 0.f ? qmax / m : 0.f;
  uint8_t qb[V];
  #pragma unroll
  for (int i = 0; i < V; ++i){
    float qf = rintf(v[i] * inv);
    if (SIGNED){
      qf = fminf(fmaxf(qf, -127.f), 127.f);
      qb[i] = (uint8_t)(int8_t)(int)qf;
    } else {
      qf = fminf(fmaxf(qf, 0.f), 255.f);
      qb[i] = (uint8_t)(int)qf;
    }
  }
  uint8_t* op = outq + (size_t)row * C + lane * V;
  if constexpr (V == 4){
    u32 p = (u32)qb[0] | ((u32)qb[1] << 8) | ((u32)qb[2] << 16) | ((u32)qb[3] << 24);
    *(u32*)op = p;
  } else if constexpr (V == 2){
    *(unsigned short*)op = (unsigned short)((u32)qb[0] | ((u32)qb[1] << 8));
  } else {
    *op = qb[0];
  }
  if (lane == 0) scales[row] = m / qmax;
}

// ---------------- mean aggregation over quantized rows ----------------
// (round-1 proven structure: 8-wide batch + scalar tail, 4B/lane row loads)

__device__ __forceinline__ float qdec(u32 w, int b, bool sgn){
  u32 byte = (w >> (8 * b)) & 0xffu;
  return sgn ? (float)(int8_t)byte : (float)byte;
}

template<int C, bool SIGNED>
__global__ __launch_bounds__(256) void agg_q8_k(const uint8_t* __restrict__ tq,
    const float* __restrict__ tsc,
    const int* __restrict__ rowptr, const int* __restrict__ csr,
    bf16_t* __restrict__ outm){
  constexpr int V = C / 64;
  int wid  = (blockIdx.x * 256 + threadIdx.x) >> 6;
  int lane = threadIdx.x & 63;
  if (wid >= NN) return;
  int beg = __builtin_amdgcn_readfirstlane(rowptr[wid]);
  int end = __builtin_amdgcn_readfirstlane(rowptr[wid + 1]);
  float acc[V];
  #pragma unroll
  for (int i = 0; i < V; ++i) acc[i] = 0.f;

  const uint8_t* hb = tq + lane * V;
  int e = beg;
  for (; e + 7 < end; e += 8){
    int   s[8]; float sc[8];
    #pragma unroll
    for (int q = 0; q < 8; ++q) s[q] = csr[e + q];
    u32 w[8];
    #pragma unroll
    for (int q = 0; q < 8; ++q){
      if constexpr (V == 4) w[q] = *(const u32*)(hb + (size_t)s[q] * C);
      else                  w[q] = *(const unsigned short*)(hb + (size_t)s[q] * C);
      sc[q] = tsc[s[q]];
    }
    #pragma unroll
    for (int q = 0; q < 8; ++q)
      #pragma unroll
      for (int i = 0; i < V; ++i)
        acc[i] += sc[q] * qdec(w[q], i, SIGNED);
  }
  for (; e < end; ++e){
    int s0 = csr[e];
    u32 w0;
    if constexpr (V == 4) w0 = *(const u32*)(hb + (size_t)s0 * C);
    else                  w0 = *(const unsigned short*)(hb + (size_t)s0 * C);
    float sc0 = tsc[s0];
    #pragma unroll
    for (int i = 0; i < V; ++i) acc[i] += sc0 * qdec(w0, i, SIGNED);
  }

  int d = end - beg;
  float di = d > 0 ? 1.0f / (float)d : 0.f;
  bf16_t* po = outm + (size_t)wid * C + lane * V;
  if constexpr (V == 2){
    u32 u = (u32)f2b(acc[0] * di) | ((u32)f2b(acc[1] * di) << 16);
    *(u32*)po = u;
  } else {
    uint2 u;
    u.x = (u32)f2b(acc[0] * di) | ((u32)f2b(acc[1] * di) << 16);
    u.y = (u32)f2b(acc[2] * di) | ((u32)f2b(acc[3] * di) << 16);
    *(uint2*)po = u;
  }
}

// ---------------- final aggregation (layer 3, C=64, int8 P) ----------------
// (round-1 proven structure)

__global__ __launch_bounds__(256) void agg_final_q8_k(
    const uint8_t* __restrict__ Pq, const float* __restrict__ scp,
    const float* __restrict__ Q,
    const int* __restrict__ rowptr, const int* __restrict__ csr,
    float* __restrict__ out){
  int wid  = (blockIdx.x * 256 + threadIdx.x) >> 6;
  int lane = threadIdx.x & 63;
  if (wid >= NN) return;
  int beg = __builtin_amdgcn_readfirstlane(rowptr[wid]);
  int end = __builtin_amdgcn_readfirstlane(rowptr[wid + 1]);
  const uint8_t* Pb = Pq + lane;
  float acc = 0.f;
  int e = beg;
  for (; e + 7 < end; e += 8){
    int s[8]; uint8_t b[8]; float sc[8];
    #pragma unroll
    for (int q = 0; q < 8; ++q) s[q] = csr[e + q];
    #pragma unroll
    for (int q = 0; q < 8; ++q){ b[q] = Pb[(size_t)s[q] * 64]; sc[q] = scp[s[q]]; }
    #pragma unroll
    for (int q = 0; q < 8; ++q) acc += sc[q] * (float)(int8_t)b[q];
  }
  for (; e < end; ++e) acc += scp[csr[e]] * (float)(int8_t)Pb[(size_t)csr[e] * 64];
  int d = end - beg;
  float di = d > 0 ? 1.0f / (float)d : 0.f;
  out[(size_t)wid * 64 + lane] = acc * di + Q[(size_t)wid * 64 + lane];
}

// ---------------- MFMA dual-GEMM + bias + BN + ReLU (layers 1,2) ----------------
// 2-phase pipeline: global_load_lds(16B) staging into XOR-swizzled linear LDS,
// double-buffered, counted s_waitcnt vmcnt(8) (never drained mid-loop),
// raw s_barrier (no compiler vmcnt(0) drain).

template<int K_>
__global__ __launch_bounds__(256) void mfma_gemm_k(
    const bf16_t* __restrict__ A0, const bf16_t* __restrict__ A1,
    const bf16_t* __restrict__ W0t, const bf16_t* __restrict__ W1t,
    const float* __restrict__ bias,
    const float* __restrict__ gamma, const float* __restrict__ beta,
    const float* __restrict__ rmean, const float* __restrict__ rvar,
    bf16_t* __restrict__ out, int M, int Nout)
{
  constexpr int BM = 128;
  constexpr int BN = 128;
  constexpr int BK = 64;
  constexpr int KT = K_ / BK;     // k-tiles per pass
  constexpr int T  = 2 * KT;      // total tiles across both passes
  __shared__ bf16_t As[2][BM * BK];
  __shared__ bf16_t Bs[2][BN * BK];

  int t    = threadIdx.x;
  int lane = t & 63;
  int wid  = t >> 6;
  int wr   = wid >> 1, wc = wid & 1;
  int l15  = lane & 15;
  int quad = lane >> 4;

  int m0 = blockIdx.x * BM;
  int n0 = blockIdx.y * BN;

  f32x4 acc[4][4];
  #pragma unroll
  for (int i = 0; i < 4; ++i)
    #pragma unroll
    for (int j = 0; j < 4; ++j)
      acc[i][j] = (f32x4){0.f, 0.f, 0.f, 0.f};

  auto stage = [&](int tile, int buf){
    const bf16_t* Ap = (tile < KT) ? A0 : A1;
    const bf16_t* Wp = (tile < KT) ? W0t : W1t;
    int k0 = ((tile < KT) ? tile : tile - KT) * BK;
    #pragma unroll
    for (int i = 0; i < 4; ++i){           // A: 1024 chunks, 4 gload/wave
      int c   = i * 256 + t;
      int row = c >> 3;
      int k8  = (c & 7) ^ (row & 7);
      int gm  = m0 + row; gm = gm < NN ? gm : NN - 1;
      GL16(Ap + (size_t)gm * K_ + k0 + k8 * 8, &As[buf][(i * 256 + (t & 192)) * 8]);
    }
    #pragma unroll
    for (int i = 0; i < 4; ++i){           // B: 1024 chunks, 4 gload/wave
      int c   = i * 256 + t;
      int row = c >> 3;
      int k8  = (c & 7) ^ (row & 7);
      GL16(Wp + (size_t)(n0 + row) * K_ + k0 + k8 * 8, &Bs[buf][(i * 256 + (t & 192)) * 8]);
    }
  };

  stage(0, 0);
  #pragma unroll
  for (int tile = 0; tile < T; ++tile){
    int buf = tile & 1;
    if (tile + 1 < T){
      stage(tile + 1, buf ^ 1);                        // issue next, no wait
      asm volatile("s_waitcnt vmcnt(8)" ::: "memory"); // current tile's 8 landed
    } else {
      asm volatile("s_waitcnt vmcnt(0)" ::: "memory");
    }
    __builtin_amdgcn_s_barrier();                      // all waves' chunks visible
    #pragma unroll
    for (int kk = 0; kk < 2; ++kk){
      bf16x8 af[4], bfr[4];
      #pragma unroll
      for (int i = 0; i < 4; ++i){
        int row = wr * 64 + i * 16 + l15;
        af[i] = *(const bf16x8*)(&As[buf][(size_t)((row << 3) + ((quad + kk * 4) ^ (row & 7))) * 8]);
      }
      #pragma unroll
      for (int j = 0; j < 4; ++j){
        int row = wc * 64 + j * 16 + l15;
        bfr[j] = *(const bf16x8*)(&Bs[buf][(size_t)((row << 3) + ((quad + kk * 4) ^ (row & 7))) * 8]);
      }
      #pragma unroll
      for (int i = 0; i < 4; ++i)
        #pragma unroll
        for (int j = 0; j < 4; ++j)
          acc[i][j] = __builtin_amdgcn_mfma_f32_16x16x32_bf16(af[i], bfr[j], acc[i][j], 0, 0, 0);
    }
    __builtin_amdgcn_s_barrier();                      // protect buf before overwrite
  }

  #pragma unroll
  for (int j = 0; j < 4; ++j){
    int col = n0 + wc * 64 + j * 16 + l15;
    float sc = gamma[col] * rsqrtf(rvar[col] + 1e-5f);
    float shift = (bias[col] - rmean[col]) * sc + beta[col];
    #pragma unroll
    for (int i = 0; i < 4; ++i){
      int rbase = m0 + wr * 64 + i * 16 + quad * 4;
      #pragma unroll
      for (int r = 0; r < 4; ++r){
        int row = rbase + r;
        if (row < M){
          float v = fmaxf(acc[i][j][r] * sc + shift, 0.f);
          out[(size_t)row * Nout + col] = f2b(v);
        }
      }
    }
  }
}

// ---------------- layer-3 GEMM with fused P-quantization ----------------
// P = A@Wcl quantized to s8 per-row IN-EPILOGUE (bf16 P never materialized);
// Q = A@Wcr + bcl (f32). wc=0 waves hold a full 64-col P row across 16 lanes
// (same quad) x 4 regs -> row absmax via 4-step quad shuffle.

__global__ __launch_bounds__(256) void gemm3_k(
    const bf16_t* __restrict__ A, const bf16_t* __restrict__ Wt,
    const float* __restrict__ bcl,
    uint8_t* __restrict__ Pq, float* __restrict__ scp,
    float* __restrict__ Q, int M)
{
  constexpr int K_ = 256, BM = 128, BK = 64;
  constexpr int T = K_ / BK;      // 4 tiles
  __shared__ bf16_t As[2][BM * BK];
  __shared__ bf16_t Bs[2][128 * BK];

  int t    = threadIdx.x;
  int lane = t & 63;
  int wid  = t >> 6;
  int wr   = wid >> 1, wc = wid & 1;
  int l15  = lane & 15;
  int quad = lane >> 4;
  int m0 = blockIdx.x * BM;

  f32x4 acc[4][4];
  #pragma unroll
  for (int i = 0; i < 4; ++i)
    #pragma unroll
    for (int j = 0; j < 4; ++j)
      acc[i][j] = (f32x4){0.f, 0.f, 0.f, 0.f};

  auto stage = [&](int tile, int buf){
    int k0 = tile * BK;
    #pragma unroll
    for (int i = 0; i < 4; ++i){
      int c   = i * 256 + t;
      int row = c >> 3;
      int k8  = (c & 7) ^ (row & 7);
      int gm  = m0 + row; gm = gm < NN ? gm : NN - 1;
      GL16(A + (size_t)gm * K_ + k0 + k8 * 8, &As[buf][(i * 256 + (t & 192)) * 8]);
    }
    #pragma unroll
    for (int i = 0; i < 4; ++i){
      int c   = i * 256 + t;
      int row = c >> 3;
      int k8  = (c & 7) ^ (row & 7);
      GL16(Wt + (size_t)row * K_ + k0 + k8 * 8, &Bs[buf][(i * 256 + (t & 192)) * 8]);
    }
  };

  stage(0, 0);
  #pragma unroll
  for (int tile = 0; tile < T; ++tile){
    int buf = tile & 1;
    if (tile + 1 < T){
      stage(tile + 1, buf ^ 1);
      asm volatile("s_waitcnt vmcnt(8)" ::: "memory");
    } else {
      asm volatile("s_waitcnt vmcnt(0)" ::: "memory");
    }
    __builtin_amdgcn_s_barrier();
    #pragma unroll
    for (int kk = 0; kk < 2; ++kk){
      bf16x8 af[4], bfr[4];
      #pragma unroll
      for (int i = 0; i < 4; ++i){
        int row = wr * 64 + i * 16 + l15;
        af[i] = *(const bf16x8*)(&As[buf][(size_t)((row << 3) + ((quad + kk * 4) ^ (row & 7))) * 8]);
      }
      #pragma unroll
      for (int j = 0; j < 4; ++j){
        int row = wc * 64 + j * 16 + l15;
        bfr[j] = *(const bf16x8*)(&Bs[buf][(size_t)((row << 3) + ((quad + kk * 4) ^ (row & 7))) * 8]);
      }
      #pragma unroll
      for (int i = 0; i < 4; ++i)
        #pragma unroll
        for (int j = 0; j < 4; ++j)
          acc[i][j] = __builtin_amdgcn_mfma_f32_16x16x32_bf16(af[i], bfr[j], acc[i][j], 0, 0, 0);
    }
    __builtin_amdgcn_s_barrier();
  }

  if (wc == 0){
    // quantize P rows in-register: row = m0 + wr*64 + i*16 + quad*4 + r
    #pragma unroll
    for (int i = 0; i < 4; ++i){
      #pragma unroll
      for (int r = 0; r < 4; ++r){
        int row = m0 + wr * 64 + i * 16 + quad * 4 + r;
        float m = 0.f;
        #pragma unroll
        for (int j = 0; j < 4; ++j) m = fmaxf(m, fabsf(acc[i][j][r]));
        #pragma unroll
        for (int msk = 1; msk < 16; msk <<= 1) m = fmaxf(m, __shfl_xor(m, msk, 64));
        float inv = m > 0.f ? 127.f / m : 0.f;
        if (row < M){
          #pragma unroll
          for (int j = 0; j < 4; ++j){
            float qf = fminf(fmaxf(rintf(acc[i][j][r] * inv), -127.f), 127.f);
            ((int8_t*)Pq)[(size_t)row * 64 + j * 16 + l15] = (int8_t)(int)qf;
          }
          if (l15 == 0) scp[row] = m / 127.f;
        }
      }
    }
  } else {
    #pragma unroll
    for (int j = 0; j < 4; ++j){
      int col = j * 16 + l15;
      float bc = bcl[col];
      #pragma unroll
      for (int i = 0; i < 4; ++i){
        int rbase = m0 + wr * 64 + i * 16 + quad * 4;
        #pragma unroll
        for (int r = 0; r < 4; ++r){
          int row = rbase + r;
          if (row < M) Q[(size_t)row * 64 + col] = acc[i][j][r] + bc;
        }
      }
    }
  }
}

// ---------------- launch ----------------

extern "C" void kernel_launch(void* const* d_in, const int* in_sizes, int n_in,
                              void* d_out, int out_size, void* d_ws, size_t ws_size,
                              hipStream_t stream)
{
  const float* x   = (const float*)d_in[0];
  const int*   ei  = (const int*)d_in[1];
  const float* W1l = (const float*)d_in[2];
  const float* b1l = (const float*)d_in[3];
  const float* W1r = (const float*)d_in[4];
  const float* g1  = (const float*)d_in[5];
  const float* be1 = (const float*)d_in[6];
  const float* rm1 = (const float*)d_in[7];
  const float* rv1 = (const float*)d_in[8];
  const float* W2l = (const float*)d_in[9];
  const float* b2l = (const float*)d_in[10];
  const float* W2r = (const float*)d_in[11];
  const float* g2  = (const float*)d_in[12];
  const float* be2 = (const float*)d_in[13];
  const float* rm2 = (const float*)d_in[14];
  const float* rv2 = (const float*)d_in[15];
  const float* Wcl = (const float*)d_in[16];
  const float* bcl = (const float*)d_in[17];
  const float* Wcr = (const float*)d_in[18];
  (void)in_sizes; (void)n_in; (void)out_size; (void)ws_size;

  char* ws = (char*)d_ws;
  size_t off = 0;
  auto alloc = [&](size_t bytes)->char* {
    char* p = ws + off;
    off += (bytes + 15) & ~(size_t)15;
    return p;
  };
  int*    bcnt   = (int*)   alloc(800 * 4);             // [NB] counts + [NB] fill (contig)
  int*    bfill  = bcnt + 400;
  int*    bbase  = (int*)   alloc((size_t)(NB + 1) * 4);
  int*    rowptr = (int*)   alloc((size_t)(NN + 1) * 4);
  int*    eflag  = (int*)   alloc(16);
  int*    csr    = (int*)   alloc((size_t)EE * 4);
  bf16_t* xb     = (bf16_t*)alloc((size_t)NN * IN_C * 2);
  bf16_t* aggb   = (bf16_t*)alloc((size_t)NN * HID_C * 2);
  bf16_t* h1     = (bf16_t*)alloc((size_t)NN * HID_C * 2);
  bf16_t* h2     = (bf16_t*)alloc((size_t)NN * HID_C * 2);
  bf16_t* W1lt   = (bf16_t*)alloc((size_t)IN_C  * HID_C * 2);
  bf16_t* W1rt   = (bf16_t*)alloc((size_t)IN_C  * HID_C * 2);
  bf16_t* W2lt   = (bf16_t*)alloc((size_t)HID_C * HID_C * 2);
  bf16_t* W2rt   = (bf16_t*)alloc((size_t)HID_C * HID_C * 2);
  bf16_t* Wc3t   = (bf16_t*)alloc((size_t)128 * HID_C * 2);  // [128][256] concat
  float*  sc1    = (float*) alloc((size_t)NN * 4);           // h1 row scales
  float*  scp    = (float*) alloc((size_t)NN * 4);           // P row scales

  // aliases into dead-by-then regions:
  uint2*   pairs = (uint2*)aggb;                     // [E] (src,dst), CSR build only
  uint8_t* xq  = (uint8_t*)h2;                       // [N,128] s8, dead before GEMM2 writes h2
  float*   scx = (float*)((char*)h2 + (size_t)NN * IN_C);
  uint8_t* h1q = (uint8_t*)xb;                       // [N,256] u8, xb dead after GEMM1
  uint8_t* Pq  = (uint8_t*)aggb;                     // [N,64] s8, aggb dead after GEMM2
  float*   Q   = (float*)h1;                         // [N,64] f32, h1 dead after GEMM2

  hipMemsetAsync(bcnt, 0, 800 * 4, stream);

  int wb = (NN + 3) / 4;        // one wave per row/node kernels
  int mblocks = (NN + 127) / 128;

  // fused x convert (bf16) + layer-1 quantize (s8): reads x once
  xconv_k<<<wb, 256, 0, stream>>>(x, xb, xq, scx);

  WtArgs wa;
  wa.W[0] = W1l; wa.Wt[0] = W1lt; wa.K[0] = IN_C;  wa.N[0] = HID_C;
  wa.W[1] = W1r; wa.Wt[1] = W1rt; wa.K[1] = IN_C;  wa.N[1] = HID_C;
  wa.W[2] = W2l; wa.Wt[2] = W2lt; wa.K[2] = HID_C; wa.N[2] = HID_C;
  wa.W[3] = W2r; wa.Wt[3] = W2rt; wa.K[3] = HID_C; wa.N[3] = HID_C;
  wa.W[4] = Wcl; wa.Wt[4] = Wc3t;             wa.K[4] = HID_C; wa.N[4] = OUT_C;
  wa.W[5] = Wcr; wa.Wt[5] = Wc3t + 64 * 256;  wa.K[5] = HID_C; wa.N[5] = OUT_C;
  wa.off[0] = 0;
  for (int s = 0; s < 6; ++s) wa.off[s + 1] = wa.off[s] + wa.K[s] * wa.N[s];
  wt_all_k<<<(wa.off[6] + 255) / 256, 256, 0, stream>>>(wa);

  // CSR build (bucketed two-phase sort)
  detect_edge_k<<<1, 256, 0, stream>>>(ei, eflag);
  bcount_k<<<K3_BLOCKS, 256, 0, stream>>>(ei, eflag, bcnt);
  bscan_k<<<1, 512, 0, stream>>>(bcnt, bbase);
  bscatter_k<<<K3_BLOCKS, 256, 0, stream>>>(ei, eflag, bbase, bfill, pairs);
  bsort_k<<<NB, 256, 0, stream>>>(pairs, bbase, rowptr, csr);

  // layer 1: agg (s8), dual GEMM -> h1 (BN+ReLU)
  agg_q8_k<IN_C, true><<<wb, 256, 0, stream>>>(xq, scx, rowptr, csr, aggb);
  dim3 g1d(mblocks, HID_C / 128);
  mfma_gemm_k<IN_C><<<g1d, 256, 0, stream>>>(
      aggb, xb, W1lt, W1rt, b1l, g1, be1, rm1, rv1, h1, NN, HID_C);

  // layer 2: quantize h1 (u8 per-row, post-ReLU), agg, dual GEMM -> h2 (BN+ReLU)
  quant_k<HID_C, false, bf16_t><<<wb, 256, 0, stream>>>(h1, h1q, sc1);
  agg_q8_k<HID_C, false><<<wb, 256, 0, stream>>>(h1q, sc1, rowptr, csr, aggb);
  mfma_gemm_k<HID_C><<<g1d, 256, 0, stream>>>(
      aggb, h1, W2lt, W2rt, b2l, g2, be2, rm2, rv2, h2, NN, HID_C);

  // layer 3 (linearity-reordered): Pq,scp = quant(h2@Wcl); Q = h2@Wcr + bcl;
  // out = agg(Pq)*scp + Q  (P-quant fused into gemm3 epilogue)
  gemm3_k<<<mblocks, 256, 0, stream>>>(h2, Wc3t, bcl, Pq, scp, Q, NN);
  agg_final_q8_k<<<wb, 256, 0, stream>>>(Pq, scp, Q, rowptr, csr, (float*)d_out);
}

// Round 5
// 542.431 us; speedup vs baseline: 1.1882x; 1.0447x over previous
//
#include <hip/hip_runtime.h>
#include <stdint.h>

#define NN 100000
#define EE 1600000
#define IN_C 128
#define HID_C 256
#define OUT_C 64

#define NB 391            // CSR buckets: 256 node-ids each (391*256 = 100096 >= NN)
#define CAP 5120          // LDS sort capacity per bucket (expected 4096, +16 sigma)
#define K3_NPT 25         // edges per thread in bucket kernels
#define K3_BLOCKS 250     // 250 * 256 * 25 = 1.6M = EE exactly

typedef unsigned short bf16_t;
typedef unsigned int u32;
typedef __attribute__((ext_vector_type(8))) short bf16x8;
typedef __attribute__((ext_vector_type(4))) float f32x4;

__device__ __forceinline__ float b2f(unsigned short u){
  unsigned int x = ((unsigned int)u) << 16;
  return __uint_as_float(x);
}
__device__ __forceinline__ unsigned short f2b(float f){
  unsigned int x = __float_as_uint(f);
  unsigned int r = x + 0x7FFFu + ((x >> 16) & 1u);   // RNE
  return (unsigned short)(r >> 16);
}

// async global->LDS, 16B per lane. LDS dest is wave-uniform base + lane*16.
#define GL16(gp, lp) __builtin_amdgcn_global_load_lds( \
    (const __attribute__((address_space(1))) void*)(gp), \
    (__attribute__((address_space(3))) void*)(lp), 16, 0, 0)

// ---------------- edge dtype detector ----------------
__global__ void detect_edge_k(const int* __restrict__ ei, int* __restrict__ eflag){
  __shared__ int sm[256];
  int t = threadIdx.x;
  int o = 0;
  for (int i = t; i < 1024; i += 256) o |= ei[2*i + 1];
  sm[t] = o; __syncthreads();
  for (int s = 128; s > 0; s >>= 1){
    if (t < s) sm[t] |= sm[t + s];
    __syncthreads();
  }
  if (t == 0) *eflag = (sm[0] == 0) ? 1 : 0;   // 1 = int64 layout
}

// ---------------- CSR build: bucketed two-phase sort ----------------
__global__ __launch_bounds__(256) void bcount_k(const int* __restrict__ ei,
    const int* __restrict__ eflag, int* __restrict__ bcnt){
  __shared__ int h[NB];
  int t = threadIdx.x;
  for (int i = t; i < NB; i += 256) h[i] = 0;
  __syncthreads();
  int i64 = *eflag;
  int base = blockIdx.x * (256 * K3_NPT);
  #pragma unroll
  for (int q = 0; q < K3_NPT; ++q){
    int e = base + q * 256 + t;
    int d = i64 ? ei[2*(EE + e)] : ei[EE + e];
    atomicAdd(&h[d >> 8], 1);
  }
  __syncthreads();
  for (int i = t; i < NB; i += 256) if (h[i]) atomicAdd(&bcnt[i], h[i]);
}

__global__ void bscan_k(const int* __restrict__ bcnt, int* __restrict__ bbase){
  __shared__ int sm[512];
  int t = threadIdx.x;
  sm[t] = (t < NB) ? bcnt[t] : 0;
  __syncthreads();
  for (int off = 1; off < 512; off <<= 1){
    int a = (t >= off) ? sm[t - off] : 0;
    __syncthreads();
    sm[t] += a;
    __syncthreads();
  }
  if (t <= NB) bbase[t] = (t == 0) ? 0 : sm[t - 1];
}

__global__ __launch_bounds__(256) void bscatter_k(const int* __restrict__ ei,
    const int* __restrict__ eflag, const int* __restrict__ bbase,
    int* __restrict__ bfill, uint2* __restrict__ pairs){
  __shared__ int cnt[NB];
  __shared__ int cnt2[NB];
  __shared__ int lbase[NB];
  int t = threadIdx.x;
  for (int i = t; i < NB; i += 256){ cnt[i] = 0; cnt2[i] = 0; }
  __syncthreads();
  int i64 = *eflag;
  int ebase = blockIdx.x * (256 * K3_NPT);
  int src[K3_NPT], dst[K3_NPT];
  #pragma unroll
  for (int q = 0; q < K3_NPT; ++q){
    int e = ebase + q * 256 + t;
    src[q] = i64 ? ei[2*e] : ei[e];
    dst[q] = i64 ? ei[2*(EE + e)] : ei[EE + e];
    atomicAdd(&cnt[dst[q] >> 8], 1);
  }
  __syncthreads();
  for (int i = t; i < NB; i += 256)
    lbase[i] = cnt[i] ? atomicAdd(&bfill[i], cnt[i]) : 0;
  __syncthreads();
  #pragma unroll
  for (int q = 0; q < K3_NPT; ++q){
    int b = dst[q] >> 8;
    int r = atomicAdd(&cnt2[b], 1);
    pairs[bbase[b] + lbase[b] + r] = make_uint2((u32)src[q], (u32)dst[q]);
  }
}

__global__ __launch_bounds__(256) void bsort_k(const uint2* __restrict__ pairs,
    const int* __restrict__ bbase, int* __restrict__ rowptr, int* __restrict__ csr){
  __shared__ int hist[256];
  __shared__ int pref[257];
  __shared__ int cnt[256];
  __shared__ int lsrc[CAP];
  int b = blockIdx.x;
  int t = threadIdx.x;
  int e0 = bbase[b], e1 = bbase[b + 1];
  int s = e1 - e0;
  hist[t] = 0; cnt[t] = 0;
  __syncthreads();
  for (int i = t; i < s; i += 256)
    atomicAdd(&hist[pairs[e0 + i].y & 255], 1);
  __syncthreads();
  for (int off = 1; off < 256; off <<= 1){
    int a = (t >= off) ? hist[t - off] : 0;
    __syncthreads();
    hist[t] += a;
    __syncthreads();
  }
  if (t == 0) pref[0] = 0;
  pref[t + 1] = hist[t];
  __syncthreads();
  int gid = b * 256 + t;
  if (gid <= NN) rowptr[gid] = e0 + pref[t];
  for (int i = t; i < s; i += 256){
    uint2 p = pairs[e0 + i];
    int bin = p.y & 255;
    int r = atomicAdd(&cnt[bin], 1);
    int pos = pref[bin] + r;
    if (pos < CAP) lsrc[pos] = (int)p.x;
    else           csr[e0 + pos] = (int)p.x;
  }
  __syncthreads();
  int lim = s < CAP ? s : CAP;
  for (int i = t; i < lim; i += 256) csr[e0 + i] = lsrc[i];
}

// ---------------- fused x convert + layer-1 quantize: one wave per row ----------------
__global__ __launch_bounds__(256) void xconv_k(const float* __restrict__ x,
    bf16_t* __restrict__ xb, uint8_t* __restrict__ xq, float* __restrict__ scx){
  int row  = (blockIdx.x * 256 + threadIdx.x) >> 6;
  int lane = threadIdx.x & 63;
  if (row >= NN) return;
  float2 u = *(const float2*)(x + (size_t)row * IN_C + lane * 2);
  u32 bb = (u32)f2b(u.x) | ((u32)f2b(u.y) << 16);
  *(u32*)(xb + (size_t)row * IN_C + lane * 2) = bb;
  float m = fmaxf(fabsf(u.x), fabsf(u.y));
  #pragma unroll
  for (int msk = 1; msk < 64; msk <<= 1) m = fmaxf(m, __shfl_xor(m, msk, 64));
  float inv = m > 0.f ? 127.f / m : 0.f;
  float qa = fminf(fmaxf(rintf(u.x * inv), -127.f), 127.f);
  float qb = fminf(fmaxf(rintf(u.y * inv), -127.f), 127.f);
  u32 pa = (u32)(uint8_t)(int8_t)(int)qa | (((u32)(uint8_t)(int8_t)(int)qb) << 8);
  *(unsigned short*)(xq + (size_t)row * IN_C + lane * 2) = (unsigned short)pa;
  if (lane == 0) scx[row] = m / 127.f;
}

// ---------------- dtype conversion (weights) ----------------
struct WtArgs {
  const float* W[6];
  bf16_t* Wt[6];
  int K[6], N[6];
  int off[7];
};

__global__ void wt_all_k(WtArgs a){
  int g = blockIdx.x * 256 + threadIdx.x;
  if (g >= a.off[6]) return;
  #pragma unroll
  for (int s = 0; s < 6; ++s){
    if (g >= a.off[s] && g < a.off[s + 1]){
      int local = g - a.off[s];
      int K = a.K[s], N = a.N[s];
      int n = local / K, k = local - n * K;
      a.Wt[s][local] = f2b(a.W[s][(size_t)k * N + n]);
    }
  }
}

// ---------------- per-row quantization: one wave per row ----------------
template<int C, bool SIGNED, typename TIN>
__global__ __launch_bounds__(256) void quant_k(const TIN* __restrict__ in,
    uint8_t* __restrict__ outq, float* __restrict__ scales){
  constexpr int V = C / 64;
  int row  = (blockIdx.x * 256 + threadIdx.x) >> 6;
  int lane = threadIdx.x & 63;
  if (row >= NN) return;
  float v[V];
  if constexpr (sizeof(TIN) == 4){
    float2 u = *(const float2*)((const float*)in + (size_t)row * C + lane * 2);
    v[0] = u.x; v[1] = u.y;
  } else {
    const bf16_t* bp = (const bf16_t*)in + (size_t)row * C + lane * V;
    if constexpr (V == 4){
      uint2 u = *(const uint2*)bp;
      v[0] = b2f((unsigned short)(u.x & 0xffffu)); v[1] = b2f((unsigned short)(u.x >> 16));
      v[2] = b2f((unsigned short)(u.y & 0xffffu)); v[3] = b2f((unsigned short)(u.y >> 16));
    } else if constexpr (V == 2){
      u32 u = *(const u32*)bp;
      v[0] = b2f((unsigned short)(u & 0xffffu)); v[1] = b2f((unsigned short)(u >> 16));
    } else {
      v[0] = b2f(*bp);
    }
  }
  float m = 0.f;
  #pragma unroll
  for (int i = 0; i < V; ++i) m = fmaxf(m, SIGNED ? fabsf(v[i]) : v[i]);
  #pragma unroll
  for (int msk = 1; msk < 64; msk <<= 1) m = fmaxf(m, __shfl_xor(m, msk, 64));
  const float qmax = SIGNED ? 127.f : 255.f;
  float inv = m > 0.f ? qmax / m : 0.f;
  uint8_t qb[V];
  #pragma unroll
  for (int i = 0; i < V; ++i){
    float qf = rintf(v[i] * inv);
    if (SIGNED){
      qf = fminf(fmaxf(qf, -127.f), 127.f);
      qb[i] = (uint8_t)(int8_t)(int)qf;
    } else {
      qf = fminf(fmaxf(qf, 0.f), 255.f);
      qb[i] = (uint8_t)(int)qf;
    }
  }
  uint8_t* op = outq + (size_t)row * C + lane * V;
  if constexpr (V == 4){
    u32 p = (u32)qb[0] | ((u32)qb[1] << 8) | ((u32)qb[2] << 16) | ((u32)qb[3] << 24);
    *(u32*)op = p;
  } else if constexpr (V == 2){
    *(unsigned short*)op = (unsigned short)((u32)qb[0] | ((u32)qb[1] << 8));
  } else {
    *op = qb[0];
  }
  if (lane == 0) scales[row] = m / qmax;
}

// ---------------- mean aggregation over quantized rows ----------------
// (round-1 proven structure: 8-wide batch + scalar tail, 4B/lane row loads)

__device__ __forceinline__ float qdec(u32 w, int b, bool sgn){
  u32 byte = (w >> (8 * b)) & 0xffu;
  return sgn ? (float)(int8_t)byte : (float)byte;
}

template<int C, bool SIGNED>
__global__ __launch_bounds__(256) void agg_q8_k(const uint8_t* __restrict__ tq,
    const float* __restrict__ tsc,
    const int* __restrict__ rowptr, const int* __restrict__ csr,
    bf16_t* __restrict__ outm){
  constexpr int V = C / 64;
  int wid  = (blockIdx.x * 256 + threadIdx.x) >> 6;
  int lane = threadIdx.x & 63;
  if (wid >= NN) return;
  int beg = __builtin_amdgcn_readfirstlane(rowptr[wid]);
  int end = __builtin_amdgcn_readfirstlane(rowptr[wid + 1]);
  float acc[V];
  #pragma unroll
  for (int i = 0; i < V; ++i) acc[i] = 0.f;

  const uint8_t* hb = tq + lane * V;
  int e = beg;
  for (; e + 7 < end; e += 8){
    int   s[8]; float sc[8];
    #pragma unroll
    for (int q = 0; q < 8; ++q) s[q] = csr[e + q];
    u32 w[8];
    #pragma unroll
    for (int q = 0; q < 8; ++q){
      if constexpr (V == 4) w[q] = *(const u32*)(hb + (size_t)s[q] * C);
      else                  w[q] = *(const unsigned short*)(hb + (size_t)s[q] * C);
      sc[q] = tsc[s[q]];
    }
    #pragma unroll
    for (int q = 0; q < 8; ++q)
      #pragma unroll
      for (int i = 0; i < V; ++i)
        acc[i] += sc[q] * qdec(w[q], i, SIGNED);
  }
  for (; e < end; ++e){
    int s0 = csr[e];
    u32 w0;
    if constexpr (V == 4) w0 = *(const u32*)(hb + (size_t)s0 * C);
    else                  w0 = *(const unsigned short*)(hb + (size_t)s0 * C);
    float sc0 = tsc[s0];
    #pragma unroll
    for (int i = 0; i < V; ++i) acc[i] += sc0 * qdec(w0, i, SIGNED);
  }

  int d = end - beg;
  float di = d > 0 ? 1.0f / (float)d : 0.f;
  bf16_t* po = outm + (size_t)wid * C + lane * V;
  if constexpr (V == 2){
    u32 u = (u32)f2b(acc[0] * di) | ((u32)f2b(acc[1] * di) << 16);
    *(u32*)po = u;
  } else {
    uint2 u;
    u.x = (u32)f2b(acc[0] * di) | ((u32)f2b(acc[1] * di) << 16);
    u.y = (u32)f2b(acc[2] * di) | ((u32)f2b(acc[3] * di) << 16);
    *(uint2*)po = u;
  }
}

// ---------------- final aggregation (layer 3, C=64, int8 P) ----------------
__global__ __launch_bounds__(256) void agg_final_q8_k(
    const uint8_t* __restrict__ Pq, const float* __restrict__ scp,
    const float* __restrict__ Q,
    const int* __restrict__ rowptr, const int* __restrict__ csr,
    float* __restrict__ out){
  int wid  = (blockIdx.x * 256 + threadIdx.x) >> 6;
  int lane = threadIdx.x & 63;
  if (wid >= NN) return;
  int beg = __builtin_amdgcn_readfirstlane(rowptr[wid]);
  int end = __builtin_amdgcn_readfirstlane(rowptr[wid + 1]);
  const uint8_t* Pb = Pq + lane;
  float acc = 0.f;
  int e = beg;
  for (; e + 7 < end; e += 8){
    int s[8]; uint8_t b[8]; float sc[8];
    #pragma unroll
    for (int q = 0; q < 8; ++q) s[q] = csr[e + q];
    #pragma unroll
    for (int q = 0; q < 8; ++q){ b[q] = Pb[(size_t)s[q] * 64]; sc[q] = scp[s[q]]; }
    #pragma unroll
    for (int q = 0; q < 8; ++q) acc += sc[q] * (float)(int8_t)b[q];
  }
  for (; e < end; ++e) acc += scp[csr[e]] * (float)(int8_t)Pb[(size_t)csr[e] * 64];
  int d = end - beg;
  float di = d > 0 ? 1.0f / (float)d : 0.f;
  out[(size_t)wid * 64 + lane] = acc * di + Q[(size_t)wid * 64 + lane];
}

// ---------------- MFMA dual-GEMM + bias + BN + ReLU (layers 1,2) ----------------
// BN=256 single-column grid: A matrices read ONCE (was twice with grid.y=2 —
// the re-read was ~100 MB of LLC->L2 traffic per GEMM, the actual bottleneck).
// BM=64, BK=64, LDS 80 KB -> 2 blocks/CU. 4 waves = 4x 64-col slices.
// Same proven 2-phase counted-vmcnt pipeline + XOR-swizzled linear LDS.

template<int K_>
__global__ __launch_bounds__(256) void mfma_gemm_k(
    const bf16_t* __restrict__ A0, const bf16_t* __restrict__ A1,
    const bf16_t* __restrict__ W0t, const bf16_t* __restrict__ W1t,
    const float* __restrict__ bias,
    const float* __restrict__ gamma, const float* __restrict__ beta,
    const float* __restrict__ rmean, const float* __restrict__ rvar,
    bf16_t* __restrict__ out, int M, int Nout)
{
  constexpr int BM = 64;
  constexpr int BN = 256;
  constexpr int BK = 64;
  constexpr int KT = K_ / BK;     // k-tiles per pass
  constexpr int T  = 2 * KT;      // total tiles across both passes
  __shared__ bf16_t As[2][BM * BK];   // 8 KB each
  __shared__ bf16_t Bs[2][BN * BK];   // 32 KB each

  int t    = threadIdx.x;
  int lane = t & 63;
  int wid  = t >> 6;              // wave = 64-col slice (0..3)
  int l15  = lane & 15;
  int quad = lane >> 4;

  int m0 = blockIdx.x * BM;

  f32x4 acc[4][4];
  #pragma unroll
  for (int i = 0; i < 4; ++i)
    #pragma unroll
    for (int j = 0; j < 4; ++j)
      acc[i][j] = (f32x4){0.f, 0.f, 0.f, 0.f};

  auto stage = [&](int tile, int buf){
    const bf16_t* Ap = (tile < KT) ? A0 : A1;
    const bf16_t* Wp = (tile < KT) ? W0t : W1t;
    int k0 = ((tile < KT) ? tile : tile - KT) * BK;
    #pragma unroll
    for (int i = 0; i < 2; ++i){           // A: 512 chunks, 2 gload/thread
      int c   = i * 256 + t;
      int row = c >> 3;
      int k8  = (c & 7) ^ (row & 7);
      int gm  = m0 + row; gm = gm < NN ? gm : NN - 1;
      GL16(Ap + (size_t)gm * K_ + k0 + k8 * 8, &As[buf][(i * 256 + (t & 192)) * 8]);
    }
    #pragma unroll
    for (int i = 0; i < 8; ++i){           // B: 2048 chunks, 8 gload/thread
      int c   = i * 256 + t;
      int row = c >> 3;
      int k8  = (c & 7) ^ (row & 7);
      GL16(Wp + (size_t)row * K_ + k0 + k8 * 8, &Bs[buf][(i * 256 + (t & 192)) * 8]);
    }
  };

  stage(0, 0);
  #pragma unroll
  for (int tile = 0; tile < T; ++tile){
    int buf = tile & 1;
    if (tile + 1 < T){
      stage(tile + 1, buf ^ 1);                         // issue next, no wait
      asm volatile("s_waitcnt vmcnt(10)" ::: "memory"); // current tile's 10 landed
    } else {
      asm volatile("s_waitcnt vmcnt(0)" ::: "memory");
    }
    __builtin_amdgcn_s_barrier();
    #pragma unroll
    for (int kk = 0; kk < 2; ++kk){
      bf16x8 af[4], bfr[4];
      #pragma unroll
      for (int i = 0; i < 4; ++i){
        int row = i * 16 + l15;
        af[i] = *(const bf16x8*)(&As[buf][(size_t)((row << 3) + ((quad + kk * 4) ^ (row & 7))) * 8]);
      }
      #pragma unroll
      for (int j = 0; j < 4; ++j){
        int row = wid * 64 + j * 16 + l15;
        bfr[j] = *(const bf16x8*)(&Bs[buf][(size_t)((row << 3) + ((quad + kk * 4) ^ (row & 7))) * 8]);
      }
      #pragma unroll
      for (int i = 0; i < 4; ++i)
        #pragma unroll
        for (int j = 0; j < 4; ++j)
          acc[i][j] = __builtin_amdgcn_mfma_f32_16x16x32_bf16(af[i], bfr[j], acc[i][j], 0, 0, 0);
    }
    __builtin_amdgcn_s_barrier();
  }

  #pragma unroll
  for (int j = 0; j < 4; ++j){
    int col = wid * 64 + j * 16 + l15;
    float sc = gamma[col] * rsqrtf(rvar[col] + 1e-5f);
    float shift = (bias[col] - rmean[col]) * sc + beta[col];
    #pragma unroll
    for (int i = 0; i < 4; ++i){
      int rbase = m0 + i * 16 + quad * 4;
      #pragma unroll
      for (int r = 0; r < 4; ++r){
        int row = rbase + r;
        if (row < M){
          float v = fmaxf(acc[i][j][r] * sc + shift, 0.f);
          out[(size_t)row * Nout + col] = f2b(v);
        }
      }
    }
  }
}

// ---------------- layer-3 GEMM with fused P-quantization ----------------
// BM=64, BN=128 (P|Q concat), K=256. LDS 48 KB -> 3 blocks/CU.
// Waves 2x2: wr in {0,1} (32-row slice), wc in {0,1} (64-col slice).
// wc=0 waves own the full 64-col P slice per row -> in-register row quant.

__global__ __launch_bounds__(256) void gemm3_k(
    const bf16_t* __restrict__ A, const bf16_t* __restrict__ Wt,
    const float* __restrict__ bcl,
    uint8_t* __restrict__ Pq, float* __restrict__ scp,
    float* __restrict__ Q, int M)
{
  constexpr int K_ = 256, BM = 64, BN = 128, BK = 64;
  constexpr int T = K_ / BK;      // 4 tiles
  __shared__ bf16_t As[2][BM * BK];   // 8 KB each
  __shared__ bf16_t Bs[2][BN * BK];   // 16 KB each

  int t    = threadIdx.x;
  int lane = t & 63;
  int wid  = t >> 6;
  int wr   = wid >> 1, wc = wid & 1;
  int l15  = lane & 15;
  int quad = lane >> 4;
  int m0 = blockIdx.x * BM;

  f32x4 acc[2][4];
  #pragma unroll
  for (int i = 0; i < 2; ++i)
    #pragma unroll
    for (int j = 0; j < 4; ++j)
      acc[i][j] = (f32x4){0.f, 0.f, 0.f, 0.f};

  auto stage = [&](int tile, int buf){
    int k0 = tile * BK;
    #pragma unroll
    for (int i = 0; i < 2; ++i){           // A: 512 chunks
      int c   = i * 256 + t;
      int row = c >> 3;
      int k8  = (c & 7) ^ (row & 7);
      int gm  = m0 + row; gm = gm < NN ? gm : NN - 1;
      GL16(A + (size_t)gm * K_ + k0 + k8 * 8, &As[buf][(i * 256 + (t & 192)) * 8]);
    }
    #pragma unroll
    for (int i = 0; i < 4; ++i){           // B: 1024 chunks
      int c   = i * 256 + t;
      int row = c >> 3;
      int k8  = (c & 7) ^ (row & 7);
      GL16(Wt + (size_t)row * K_ + k0 + k8 * 8, &Bs[buf][(i * 256 + (t & 192)) * 8]);
    }
  };

  stage(0, 0);
  #pragma unroll
  for (int tile = 0; tile < T; ++tile){
    int buf = tile & 1;
    if (tile + 1 < T){
      stage(tile + 1, buf ^ 1);
      asm volatile("s_waitcnt vmcnt(6)" ::: "memory");
    } else {
      asm volatile("s_waitcnt vmcnt(0)" ::: "memory");
    }
    __builtin_amdgcn_s_barrier();
    #pragma unroll
    for (int kk = 0; kk < 2; ++kk){
      bf16x8 af[2], bfr[4];
      #pragma unroll
      for (int i = 0; i < 2; ++i){
        int row = wr * 32 + i * 16 + l15;
        af[i] = *(const bf16x8*)(&As[buf][(size_t)((row << 3) + ((quad + kk * 4) ^ (row & 7))) * 8]);
      }
      #pragma unroll
      for (int j = 0; j < 4; ++j){
        int row = wc * 64 + j * 16 + l15;
        bfr[j] = *(const bf16x8*)(&Bs[buf][(size_t)((row << 3) + ((quad + kk * 4) ^ (row & 7))) * 8]);
      }
      #pragma unroll
      for (int i = 0; i < 2; ++i)
        #pragma unroll
        for (int j = 0; j < 4; ++j)
          acc[i][j] = __builtin_amdgcn_mfma_f32_16x16x32_bf16(af[i], bfr[j], acc[i][j], 0, 0, 0);
    }
    __builtin_amdgcn_s_barrier();
  }

  if (wc == 0){
    // quantize P rows in-register: row = m0 + wr*32 + i*16 + quad*4 + r
    #pragma unroll
    for (int i = 0; i < 2; ++i){
      #pragma unroll
      for (int r = 0; r < 4; ++r){
        int row = m0 + wr * 32 + i * 16 + quad * 4 + r;
        float m = 0.f;
        #pragma unroll
        for (int j = 0; j < 4; ++j) m = fmaxf(m, fabsf(acc[i][j][r]));
        #pragma unroll
        for (int msk = 1; msk < 16; msk <<= 1) m = fmaxf(m, __shfl_xor(m, msk, 64));
        float inv = m > 0.f ? 127.f / m : 0.f;
        if (row < M){
          #pragma unroll
          for (int j = 0; j < 4; ++j){
            float qf = fminf(fmaxf(rintf(acc[i][j][r] * inv), -127.f), 127.f);
            ((int8_t*)Pq)[(size_t)row * 64 + j * 16 + l15] = (int8_t)(int)qf;
          }
          if (l15 == 0) scp[row] = m / 127.f;
        }
      }
    }
  } else {
    #pragma unroll
    for (int j = 0; j < 4; ++j){
      int col = j * 16 + l15;
      float bc = bcl[col];
      #pragma unroll
      for (int i = 0; i < 2; ++i){
        int rbase = m0 + wr * 32 + i * 16 + quad * 4;
        #pragma unroll
        for (int r = 0; r < 4; ++r){
          int row = rbase + r;
          if (row < M) Q[(size_t)row * 64 + col] = acc[i][j][r] + bc;
        }
      }
    }
  }
}

// ---------------- launch ----------------

extern "C" void kernel_launch(void* const* d_in, const int* in_sizes, int n_in,
                              void* d_out, int out_size, void* d_ws, size_t ws_size,
                              hipStream_t stream)
{
  const float* x   = (const float*)d_in[0];
  const int*   ei  = (const int*)d_in[1];
  const float* W1l = (const float*)d_in[2];
  const float* b1l = (const float*)d_in[3];
  const float* W1r = (const float*)d_in[4];
  const float* g1  = (const float*)d_in[5];
  const float* be1 = (const float*)d_in[6];
  const float* rm1 = (const float*)d_in[7];
  const float* rv1 = (const float*)d_in[8];
  const float* W2l = (const float*)d_in[9];
  const float* b2l = (const float*)d_in[10];
  const float* W2r = (const float*)d_in[11];
  const float* g2  = (const float*)d_in[12];
  const float* be2 = (const float*)d_in[13];
  const float* rm2 = (const float*)d_in[14];
  const float* rv2 = (const float*)d_in[15];
  const float* Wcl = (const float*)d_in[16];
  const float* bcl = (const float*)d_in[17];
  const float* Wcr = (const float*)d_in[18];
  (void)in_sizes; (void)n_in; (void)out_size; (void)ws_size;

  char* ws = (char*)d_ws;
  size_t off = 0;
  auto alloc = [&](size_t bytes)->char* {
    char* p = ws + off;
    off += (bytes + 15) & ~(size_t)15;
    return p;
  };
  int*    bcnt   = (int*)   alloc(800 * 4);             // [NB] counts + [NB] fill (contig)
  int*    bfill  = bcnt + 400;
  int*    bbase  = (int*)   alloc((size_t)(NB + 1) * 4);
  int*    rowptr = (int*)   alloc((size_t)(NN + 1) * 4);
  int*    eflag  = (int*)   alloc(16);
  int*    csr    = (int*)   alloc((size_t)EE * 4);
  bf16_t* xb     = (bf16_t*)alloc((size_t)NN * IN_C * 2);
  bf16_t* aggb   = (bf16_t*)alloc((size_t)NN * HID_C * 2);
  bf16_t* h1     = (bf16_t*)alloc((size_t)NN * HID_C * 2);
  bf16_t* h2     = (bf16_t*)alloc((size_t)NN * HID_C * 2);
  bf16_t* W1lt   = (bf16_t*)alloc((size_t)IN_C  * HID_C * 2);
  bf16_t* W1rt   = (bf16_t*)alloc((size_t)IN_C  * HID_C * 2);
  bf16_t* W2lt   = (bf16_t*)alloc((size_t)HID_C * HID_C * 2);
  bf16_t* W2rt   = (bf16_t*)alloc((size_t)HID_C * HID_C * 2);
  bf16_t* Wc3t   = (bf16_t*)alloc((size_t)128 * HID_C * 2);  // [128][256] concat
  float*  sc1    = (float*) alloc((size_t)NN * 4);           // h1 row scales
  float*  scp    = (float*) alloc((size_t)NN * 4);           // P row scales

  // aliases into dead-by-then regions:
  uint2*   pairs = (uint2*)aggb;                     // [E] (src,dst), CSR build only
  uint8_t* xq  = (uint8_t*)h2;                       // [N,128] s8, dead before GEMM2 writes h2
  float*   scx = (float*)((char*)h2 + (size_t)NN * IN_C);
  uint8_t* h1q = (uint8_t*)xb;                       // [N,256] u8, xb dead after GEMM1
  uint8_t* Pq  = (uint8_t*)aggb;                     // [N,64] s8, aggb dead after GEMM2
  float*   Q   = (float*)h1;                         // [N,64] f32, h1 dead after GEMM2

  hipMemsetAsync(bcnt, 0, 800 * 4, stream);

  int wb = (NN + 3) / 4;           // one wave per row/node kernels
  int g64 = (NN + 63) / 64;        // BM=64 GEMM grids

  // fused x convert (bf16) + layer-1 quantize (s8): reads x once
  xconv_k<<<wb, 256, 0, stream>>>(x, xb, xq, scx);

  WtArgs wa;
  wa.W[0] = W1l; wa.Wt[0] = W1lt; wa.K[0] = IN_C;  wa.N[0] = HID_C;
  wa.W[1] = W1r; wa.Wt[1] = W1rt; wa.K[1] = IN_C;  wa.N[1] = HID_C;
  wa.W[2] = W2l; wa.Wt[2] = W2lt; wa.K[2] = HID_C; wa.N[2] = HID_C;
  wa.W[3] = W2r; wa.Wt[3] = W2rt; wa.K[3] = HID_C; wa.N[3] = HID_C;
  wa.W[4] = Wcl; wa.Wt[4] = Wc3t;             wa.K[4] = HID_C; wa.N[4] = OUT_C;
  wa.W[5] = Wcr; wa.Wt[5] = Wc3t + 64 * 256;  wa.K[5] = HID_C; wa.N[5] = OUT_C;
  wa.off[0] = 0;
  for (int s = 0; s < 6; ++s) wa.off[s + 1] = wa.off[s] + wa.K[s] * wa.N[s];
  wt_all_k<<<(wa.off[6] + 255) / 256, 256, 0, stream>>>(wa);

  // CSR build (bucketed two-phase sort)
  detect_edge_k<<<1, 256, 0, stream>>>(ei, eflag);
  bcount_k<<<K3_BLOCKS, 256, 0, stream>>>(ei, eflag, bcnt);
  bscan_k<<<1, 512, 0, stream>>>(bcnt, bbase);
  bscatter_k<<<K3_BLOCKS, 256, 0, stream>>>(ei, eflag, bbase, bfill, pairs);
  bsort_k<<<NB, 256, 0, stream>>>(pairs, bbase, rowptr, csr);

  // layer 1: agg (s8), dual GEMM -> h1 (BN+ReLU)
  agg_q8_k<IN_C, true><<<wb, 256, 0, stream>>>(xq, scx, rowptr, csr, aggb);
  mfma_gemm_k<IN_C><<<g64, 256, 0, stream>>>(
      aggb, xb, W1lt, W1rt, b1l, g1, be1, rm1, rv1, h1, NN, HID_C);

  // layer 2: quantize h1 (u8 per-row, post-ReLU), agg, dual GEMM -> h2 (BN+ReLU)
  quant_k<HID_C, false, bf16_t><<<wb, 256, 0, stream>>>(h1, h1q, sc1);
  agg_q8_k<HID_C, false><<<wb, 256, 0, stream>>>(h1q, sc1, rowptr, csr, aggb);
  mfma_gemm_k<HID_C><<<g64, 256, 0, stream>>>(
      aggb, h1, W2lt, W2rt, b2l, g2, be2, rm2, rv2, h2, NN, HID_C);

  // layer 3 (linearity-reordered): Pq,scp = quant(h2@Wcl); Q = h2@Wcr + bcl;
  // out = agg(Pq)*scp + Q  (P-quant fused into gemm3 epilogue)
  gemm3_k<<<g64, 256, 0, stream>>>(h2, Wc3t, bcl, Pq, scp, Q, NN);
  agg_final_q8_k<<<wb, 256, 0, stream>>>(Pq, scp, Q, rowptr, csr, (float*)d_out);
}